// Round 1
// baseline (817.665 us; speedup 1.0000x reference)
//
#include <hip/hip_runtime.h>
#include <cstdint>
#include <cstddef>

#define NEG 0.2f

// ---------------- CSR build ----------------

__global__ __launch_bounds__(256) void hist_k(const int* __restrict__ ei, int* __restrict__ cnt, int E) {
    int i = blockIdx.x * 256 + threadIdx.x;
    if (i < E) atomicAdd(&cnt[ei[E + i]], 1);
}

__global__ __launch_bounds__(256) void scan1_k(const int* __restrict__ cnt, int* __restrict__ rp,
                                               int* __restrict__ bs, int N) {
    __shared__ int sm[256];
    int t = threadIdx.x, i = blockIdx.x * 256 + t;
    int v = (i < N) ? cnt[i] : 0;
    sm[t] = v; __syncthreads();
    for (int off = 1; off < 256; off <<= 1) {
        int u = (t >= off) ? sm[t - off] : 0;
        __syncthreads();
        sm[t] += u;
        __syncthreads();
    }
    if (i < N) rp[i] = sm[t] - v;          // exclusive within block
    if (t == 255) bs[blockIdx.x] = sm[255];
}

__global__ __launch_bounds__(1024) void scan2_k(int* __restrict__ bs, int nb) {
    __shared__ int sm[1024];
    int t = threadIdx.x;
    int v = (t < nb) ? bs[t] : 0;
    sm[t] = v; __syncthreads();
    for (int off = 1; off < 1024; off <<= 1) {
        int u = (t >= off) ? sm[t - off] : 0;
        __syncthreads();
        sm[t] += u;
        __syncthreads();
    }
    if (t < nb) bs[t] = sm[t] - v;         // exclusive block offsets
}

__global__ __launch_bounds__(256) void scan3_k(int* __restrict__ rp, const int* __restrict__ bs, int N) {
    int i = blockIdx.x * 256 + threadIdx.x;
    if (i < N) rp[i] += bs[blockIdx.x];
}

__global__ __launch_bounds__(256) void scatter_k(const int* __restrict__ ei, const int* __restrict__ rp,
                                                 int* __restrict__ cur, int* __restrict__ col, int E) {
    int i = blockIdx.x * 256 + threadIdx.x;
    if (i < E) {
        int s = ei[i], d = ei[E + i];
        int pos = rp[d] + atomicAdd(&cur[d], 1);
        col[pos] = s;
    }
}

// ---------------- Layer 1 GEMM: h1 = x @ W1 ; al_src/al_dst epilogue ----------------
// x [N,128], W1 [128,64]. One wave per row; lane c computes h1[r][c].

__global__ __launch_bounds__(256) void gemm1_k(const float* __restrict__ x, const float* __restrict__ W,
                                               const float* __restrict__ a_src, const float* __restrict__ a_dst,
                                               float* __restrict__ h, float* __restrict__ alsrc,
                                               float* __restrict__ aldst, int N) {
    __shared__ float Ws[128 * 64];
    __shared__ float xs[4][128];
    for (int i = threadIdx.x; i < 128 * 64 / 4; i += 256)
        ((float4*)Ws)[i] = ((const float4*)W)[i];

    int wave = threadIdx.x >> 6;
    int lane = threadIdx.x & 63;
    int head = lane >> 4, idx = lane & 15;
    float asv = a_src[head * 16 + idx];
    float adv = a_dst[head * 16 + idx];
    __syncthreads();

    for (int r0 = blockIdx.x * 4; r0 < N; r0 += gridDim.x * 4) {
        __syncthreads();
        for (int i = threadIdx.x; i < 4 * 128 / 4; i += 256) {
            int rr = i >> 5, kk = i & 31;
            int r = r0 + rr;
            float4 v = (r < N) ? ((const float4*)(x + (size_t)r * 128))[kk] : make_float4(0, 0, 0, 0);
            ((float4*)xs[rr])[kk] = v;
        }
        __syncthreads();
        int r = r0 + wave;
        if (r < N) {
            float acc = 0.f;
            const float* xr = xs[wave];
            #pragma unroll 8
            for (int k = 0; k < 128; k++) acc = fmaf(xr[k], Ws[k * 64 + lane], acc);
            h[(size_t)r * 64 + lane] = acc;
            float vs = acc * asv, vd = acc * adv;
            #pragma unroll
            for (int off = 8; off >= 1; off >>= 1) {
                vs += __shfl_xor(vs, off, 16);
                vd += __shfl_xor(vd, off, 16);
            }
            if (idx == 0) { alsrc[r * 4 + head] = vs; aldst[r * 4 + head] = vd; }
        }
    }
}

// ---------------- Layer 1 node aggregation (softmax + weighted sum, no atomics) ----------------
// One wave per dst node; lane c owns feature c of the 64-wide concat output.

__global__ __launch_bounds__(256) void node1_k(const float* __restrict__ h, const float* __restrict__ alsrc,
                                               const float* __restrict__ aldst, const int* __restrict__ rp,
                                               const int* __restrict__ cnt, const int* __restrict__ col,
                                               const float* __restrict__ bias, float* __restrict__ out, int N) {
    int wid = (blockIdx.x * 256 + threadIdx.x) >> 6;
    int lane = threadIdx.x & 63;
    if (wid >= N) return;
    int d = wid;
    int head = lane >> 4;
    float ad = aldst[d * 4 + head];
    // self loop
    float e0 = alsrc[d * 4 + head] + ad;
    float w = __expf(e0 > 0.f ? e0 : NEG * e0);
    float denom = w;
    float acc = w * h[(size_t)d * 64 + lane];
    int start = rp[d], deg = cnt[d];
    for (int i = 0; i < deg; i++) {
        int s = col[start + i];
        float e = alsrc[s * 4 + head] + ad;
        float we = __expf(e > 0.f ? e : NEG * e);
        denom += we;
        acc = fmaf(we, h[(size_t)s * 64 + lane], acc);
    }
    out[(size_t)d * 64 + lane] = acc / denom + bias[lane];
}

// ---------------- Layer 2 GEMM: h2 = h1o @ W2 ; al epilogue ----------------
// h1o [N,64], W2 [64,128]. One wave per row; lane owns cols {lane, lane+64}.

__global__ __launch_bounds__(256) void gemm2_k(const float* __restrict__ x, const float* __restrict__ W,
                                               const float* __restrict__ a_src, const float* __restrict__ a_dst,
                                               float* __restrict__ h, float* __restrict__ alsrc,
                                               float* __restrict__ aldst, int N) {
    __shared__ float Ws[64 * 128];
    __shared__ float xs[4][64];
    for (int i = threadIdx.x; i < 64 * 128 / 4; i += 256)
        ((float4*)Ws)[i] = ((const float4*)W)[i];

    int wave = threadIdx.x >> 6;
    int lane = threadIdx.x & 63;
    float as0 = a_src[lane], as1 = a_src[64 + lane];
    float ad0 = a_dst[lane], ad1 = a_dst[64 + lane];
    __syncthreads();

    for (int r0 = blockIdx.x * 4; r0 < N; r0 += gridDim.x * 4) {
        __syncthreads();
        for (int i = threadIdx.x; i < 4 * 64 / 4; i += 256) {
            int rr = i >> 4, kk = i & 15;
            int r = r0 + rr;
            float4 v = (r < N) ? ((const float4*)(x + (size_t)r * 64))[kk] : make_float4(0, 0, 0, 0);
            ((float4*)xs[rr])[kk] = v;
        }
        __syncthreads();
        int r = r0 + wave;
        if (r < N) {
            float acc0 = 0.f, acc1 = 0.f;
            const float* xr = xs[wave];
            #pragma unroll 8
            for (int k = 0; k < 64; k++) {
                float xv = xr[k];
                acc0 = fmaf(xv, Ws[k * 128 + lane], acc0);
                acc1 = fmaf(xv, Ws[k * 128 + 64 + lane], acc1);
            }
            h[(size_t)r * 128 + lane] = acc0;
            h[(size_t)r * 128 + 64 + lane] = acc1;
            // heads: acc0 -> head lane>>5 ; acc1 -> head 2+(lane>>5)
            float vs0 = acc0 * as0, vs1 = acc1 * as1;
            float vd0 = acc0 * ad0, vd1 = acc1 * ad1;
            #pragma unroll
            for (int off = 16; off >= 1; off >>= 1) {
                vs0 += __shfl_xor(vs0, off, 32);
                vs1 += __shfl_xor(vs1, off, 32);
                vd0 += __shfl_xor(vd0, off, 32);
                vd1 += __shfl_xor(vd1, off, 32);
            }
            if ((lane & 31) == 0) {
                int g = lane >> 5;
                alsrc[r * 4 + g] = vs0;     alsrc[r * 4 + 2 + g] = vs1;
                aldst[r * 4 + g] = vd0;     aldst[r * 4 + 2 + g] = vd1;
            }
        }
    }
}

// ---------------- Layer 2 node aggregation + head-mean + bias + ELU + log_softmax ----------------
// One wave per dst node; lane owns elements {lane, lane+64} of the [4,32] head grid.

__global__ __launch_bounds__(256) void node2_k(const float* __restrict__ h, const float* __restrict__ alsrc,
                                               const float* __restrict__ aldst, const int* __restrict__ rp,
                                               const int* __restrict__ cnt, const int* __restrict__ col,
                                               const float* __restrict__ bias, float* __restrict__ out, int N) {
    int wid = (blockIdx.x * 256 + threadIdx.x) >> 6;
    int lane = threadIdx.x & 63;
    if (wid >= N) return;
    int d = wid;
    int g = lane >> 5;          // 0/1
    int h0 = g, h1 = 2 + g;
    float adv0 = aldst[d * 4 + h0], adv1 = aldst[d * 4 + h1];
    float e0 = alsrc[d * 4 + h0] + adv0, e1 = alsrc[d * 4 + h1] + adv1;
    float w0 = __expf(e0 > 0.f ? e0 : NEG * e0);
    float w1 = __expf(e1 > 0.f ? e1 : NEG * e1);
    float den0 = w0, den1 = w1;
    float acc0 = w0 * h[(size_t)d * 128 + lane];
    float acc1 = w1 * h[(size_t)d * 128 + 64 + lane];
    int start = rp[d], deg = cnt[d];
    for (int i = 0; i < deg; i++) {
        int s = col[start + i];
        float es0 = alsrc[s * 4 + h0] + adv0;
        float es1 = alsrc[s * 4 + h1] + adv1;
        float we0 = __expf(es0 > 0.f ? es0 : NEG * es0);
        float we1 = __expf(es1 > 0.f ? es1 : NEG * es1);
        den0 += we0; den1 += we1;
        acc0 = fmaf(we0, h[(size_t)s * 128 + lane], acc0);
        acc1 = fmaf(we1, h[(size_t)s * 128 + 64 + lane], acc1);
    }
    float t = acc0 / den0 + acc1 / den1;    // heads {g, 2+g} at column lane&31
    t += __shfl_xor(t, 32);                 // + heads {1-g, 3-g}: all 4 heads
    float val = 0.25f * t + bias[lane & 31];
    float ev = val > 0.f ? val : expm1f(val);
    // log_softmax over the 32 columns (duplicated in both half-waves)
    float mx = ev;
    #pragma unroll
    for (int off = 16; off >= 1; off >>= 1) mx = fmaxf(mx, __shfl_xor(mx, off, 32));
    float ex = __expf(ev - mx), sum = ex;
    #pragma unroll
    for (int off = 16; off >= 1; off >>= 1) sum += __shfl_xor(sum, off, 32);
    float res = ev - mx - __logf(sum);
    if (lane < 32) out[(size_t)d * 32 + lane] = res;
}

// ---------------- launch ----------------

extern "C" void kernel_launch(void* const* d_in, const int* in_sizes, int n_in,
                              void* d_out, int out_size, void* d_ws, size_t ws_size,
                              hipStream_t stream) {
    const float* x   = (const float*)d_in[0];
    const int*   ei  = (const int*)d_in[1];
    const float* W1  = (const float*)d_in[2];
    const float* as1 = (const float*)d_in[3];
    const float* ad1 = (const float*)d_in[4];
    const float* b1  = (const float*)d_in[5];
    const float* W2  = (const float*)d_in[6];
    const float* as2 = (const float*)d_in[7];
    const float* ad2 = (const float*)d_in[8];
    const float* b2  = (const float*)d_in[9];
    float* out = (float*)d_out;
    int N = in_sizes[0] / 128;
    int E = in_sizes[1] / 2;

    char* base = (char*)d_ws;
    size_t off = 0;
    auto alloc = [&](size_t bytes) -> char* {
        char* p = base + off;
        off = (off + bytes + 255) & ~(size_t)255;
        return p;
    };
    float* h1     = (float*)alloc((size_t)N * 64 * 4);
    float* h1o    = (float*)alloc((size_t)N * 64 * 4);
    float* h2     = (float*)alloc((size_t)N * 128 * 4);
    float* alsrc1 = (float*)alloc((size_t)N * 4 * 4);
    float* aldst1 = (float*)alloc((size_t)N * 4 * 4);
    float* alsrc2 = (float*)alloc((size_t)N * 4 * 4);
    float* aldst2 = (float*)alloc((size_t)N * 4 * 4);
    int* cnt = (int*)alloc((size_t)N * 4);
    int* rp  = (int*)alloc((size_t)N * 4);
    int* cur = (int*)alloc((size_t)N * 4);
    int* bs  = (int*)alloc(1024 * 4);
    int* col = (int*)alloc((size_t)E * 4);

    int nb = (N + 255) / 256;
    hipMemsetAsync(cnt, 0, (size_t)N * 4, stream);
    hipMemsetAsync(cur, 0, (size_t)N * 4, stream);
    hist_k<<<(E + 255) / 256, 256, 0, stream>>>(ei, cnt, E);
    scan1_k<<<nb, 256, 0, stream>>>(cnt, rp, bs, N);
    scan2_k<<<1, 1024, 0, stream>>>(bs, nb);
    scan3_k<<<nb, 256, 0, stream>>>(rp, bs, N);
    scatter_k<<<(E + 255) / 256, 256, 0, stream>>>(ei, rp, cur, col, E);

    gemm1_k<<<1024, 256, 0, stream>>>(x, W1, as1, ad1, h1, alsrc1, aldst1, N);
    node1_k<<<(N + 3) / 4, 256, 0, stream>>>(h1, alsrc1, aldst1, rp, cnt, col, b1, h1o, N);
    gemm2_k<<<1024, 256, 0, stream>>>(h1o, W2, as2, ad2, h2, alsrc2, aldst2, N);
    node2_k<<<(N + 3) / 4, 256, 0, stream>>>(h2, alsrc2, aldst2, rp, cnt, col, b2, out, N);
}

// Round 2
// 636.174 us; speedup vs baseline: 1.2853x; 1.2853x over previous
//
#include <hip/hip_runtime.h>
#include <hip/hip_fp16.h>
#include <cstdint>
#include <cstddef>

#define NEG 0.2f

// ---------------- CSR build ----------------

__global__ __launch_bounds__(256) void hist_k(const int* __restrict__ ei, int* __restrict__ cnt, int E) {
    int i = blockIdx.x * 256 + threadIdx.x;
    if (i < E) atomicAdd(&cnt[ei[E + i]], 1);
}

__global__ __launch_bounds__(256) void scan1_k(const int* __restrict__ cnt, int* __restrict__ rp,
                                               int* __restrict__ bs, int N) {
    __shared__ int sm[256];
    int t = threadIdx.x, i = blockIdx.x * 256 + t;
    int v = (i < N) ? cnt[i] : 0;
    sm[t] = v; __syncthreads();
    for (int off = 1; off < 256; off <<= 1) {
        int u = (t >= off) ? sm[t - off] : 0;
        __syncthreads();
        sm[t] += u;
        __syncthreads();
    }
    if (i < N) rp[i] = sm[t] - v;          // exclusive within block
    if (t == 255) bs[blockIdx.x] = sm[255];
}

__global__ __launch_bounds__(1024) void scan2_k(int* __restrict__ bs, int nb) {
    __shared__ int sm[1024];
    int t = threadIdx.x;
    int v = (t < nb) ? bs[t] : 0;
    sm[t] = v; __syncthreads();
    for (int off = 1; off < 1024; off <<= 1) {
        int u = (t >= off) ? sm[t - off] : 0;
        __syncthreads();
        sm[t] += u;
        __syncthreads();
    }
    if (t < nb) bs[t] = sm[t] - v;         // exclusive block offsets
}

__global__ __launch_bounds__(256) void scan3_k(int* __restrict__ rp, const int* __restrict__ bs, int N) {
    int i = blockIdx.x * 256 + threadIdx.x;
    if (i < N) rp[i] += bs[blockIdx.x];
}

__global__ __launch_bounds__(256) void scatter_k(const int* __restrict__ ei, const int* __restrict__ rp,
                                                 int* __restrict__ cur, int* __restrict__ col, int E) {
    int i = blockIdx.x * 256 + threadIdx.x;
    if (i < E) {
        int s = ei[i], d = ei[E + i];
        int pos = rp[d] + atomicAdd(&cur[d], 1);
        col[pos] = s;
    }
}

// ---------------- Layer 1 GEMM: h1 = x @ W1 (fp16 out) ; al_src/al_dst epilogue ----------------

__global__ __launch_bounds__(256) void gemm1_k(const float* __restrict__ x, const float* __restrict__ W,
                                               const float* __restrict__ a_src, const float* __restrict__ a_dst,
                                               __half* __restrict__ h, float* __restrict__ alsrc,
                                               float* __restrict__ aldst, int N) {
    __shared__ float Ws[128 * 64];
    __shared__ float xs[4][128];
    for (int i = threadIdx.x; i < 128 * 64 / 4; i += 256)
        ((float4*)Ws)[i] = ((const float4*)W)[i];

    int wave = threadIdx.x >> 6;
    int lane = threadIdx.x & 63;
    int head = lane >> 4, idx = lane & 15;
    float asv = a_src[head * 16 + idx];
    float adv = a_dst[head * 16 + idx];
    __syncthreads();

    for (int r0 = blockIdx.x * 4; r0 < N; r0 += gridDim.x * 4) {
        __syncthreads();
        for (int i = threadIdx.x; i < 4 * 128 / 4; i += 256) {
            int rr = i >> 5, kk = i & 31;
            int r = r0 + rr;
            float4 v = (r < N) ? ((const float4*)(x + (size_t)r * 128))[kk] : make_float4(0, 0, 0, 0);
            ((float4*)xs[rr])[kk] = v;
        }
        __syncthreads();
        int r = r0 + wave;
        if (r < N) {
            float acc = 0.f;
            const float* xr = xs[wave];
            #pragma unroll 8
            for (int k = 0; k < 128; k++) acc = fmaf(xr[k], Ws[k * 64 + lane], acc);
            h[(size_t)r * 64 + lane] = __float2half(acc);
            float vs = acc * asv, vd = acc * adv;
            #pragma unroll
            for (int off = 8; off >= 1; off >>= 1) {
                vs += __shfl_xor(vs, off, 16);
                vd += __shfl_xor(vd, off, 16);
            }
            if (idx == 0) { alsrc[r * 4 + head] = vs; aldst[r * 4 + head] = vd; }
        }
    }
}

// ---------------- Layer 1 node aggregation ----------------
// One wave per dst node. Quarter-wave g in {0..3} handles edges i = g, g+4, ...
// Lane owns cols 4c..4c+3 (c = lane & 15), head = c >> 2. Partials combined via shfl_xor.

__global__ __launch_bounds__(256) void node1_k(const __half* __restrict__ h, const float* __restrict__ alsrc,
                                               const float* __restrict__ aldst, const int* __restrict__ rp,
                                               const int* __restrict__ cnt, const int* __restrict__ col,
                                               const float* __restrict__ bias, float* __restrict__ out, int N) {
    int wid = (blockIdx.x * 256 + threadIdx.x) >> 6;
    int lane = threadIdx.x & 63;
    if (wid >= N) return;
    int d = wid;
    int g = lane >> 4;
    int c = lane & 15;
    int head = c >> 2;
    float ad = aldst[d * 4 + head];
    float den = 0.f;
    float a0 = 0, a1 = 0, a2 = 0, a3 = 0;
    if (g == 0) {  // self loop
        float e0 = alsrc[d * 4 + head] + ad;
        float w = __expf(e0 > 0.f ? e0 : NEG * e0);
        den = w;
        uint2 u = *(const uint2*)(h + (size_t)d * 64 + 4 * c);
        __half2 p0 = *(__half2*)&u.x, p1 = *(__half2*)&u.y;
        float2 f0 = __half22float2(p0), f1 = __half22float2(p1);
        a0 = w * f0.x; a1 = w * f0.y; a2 = w * f1.x; a3 = w * f1.y;
    }
    int start = rp[d], deg = cnt[d];
    for (int i = g; i < deg; i += 4) {
        int s = col[start + i];
        float e = alsrc[s * 4 + head] + ad;
        float w = __expf(e > 0.f ? e : NEG * e);
        den += w;
        uint2 u = *(const uint2*)(h + (size_t)s * 64 + 4 * c);
        __half2 p0 = *(__half2*)&u.x, p1 = *(__half2*)&u.y;
        float2 f0 = __half22float2(p0), f1 = __half22float2(p1);
        a0 = fmaf(w, f0.x, a0); a1 = fmaf(w, f0.y, a1);
        a2 = fmaf(w, f1.x, a2); a3 = fmaf(w, f1.y, a3);
    }
    #pragma unroll
    for (int off = 16; off <= 32; off <<= 1) {
        a0 += __shfl_xor(a0, off); a1 += __shfl_xor(a1, off);
        a2 += __shfl_xor(a2, off); a3 += __shfl_xor(a3, off);
        den += __shfl_xor(den, off);
    }
    if (lane < 16) {
        float inv = 1.f / den;
        float4 b = *(const float4*)(bias + 4 * c);
        float4 o;
        o.x = a0 * inv + b.x; o.y = a1 * inv + b.y;
        o.z = a2 * inv + b.z; o.w = a3 * inv + b.w;
        *(float4*)(out + (size_t)d * 64 + 4 * c) = o;
    }
}

// ---------------- Layer 2 GEMM: h2 = h1o @ W2 (fp16 out) ; al epilogue ----------------

__global__ __launch_bounds__(256) void gemm2_k(const float* __restrict__ x, const float* __restrict__ W,
                                               const float* __restrict__ a_src, const float* __restrict__ a_dst,
                                               __half* __restrict__ h, float* __restrict__ alsrc,
                                               float* __restrict__ aldst, int N) {
    __shared__ float Ws[64 * 128];
    __shared__ float xs[4][64];
    for (int i = threadIdx.x; i < 64 * 128 / 4; i += 256)
        ((float4*)Ws)[i] = ((const float4*)W)[i];

    int wave = threadIdx.x >> 6;
    int lane = threadIdx.x & 63;
    float as0 = a_src[lane], as1 = a_src[64 + lane];
    float ad0 = a_dst[lane], ad1 = a_dst[64 + lane];
    __syncthreads();

    for (int r0 = blockIdx.x * 4; r0 < N; r0 += gridDim.x * 4) {
        __syncthreads();
        for (int i = threadIdx.x; i < 4 * 64 / 4; i += 256) {
            int rr = i >> 4, kk = i & 15;
            int r = r0 + rr;
            float4 v = (r < N) ? ((const float4*)(x + (size_t)r * 64))[kk] : make_float4(0, 0, 0, 0);
            ((float4*)xs[rr])[kk] = v;
        }
        __syncthreads();
        int r = r0 + wave;
        if (r < N) {
            float acc0 = 0.f, acc1 = 0.f;
            const float* xr = xs[wave];
            #pragma unroll 8
            for (int k = 0; k < 64; k++) {
                float xv = xr[k];
                acc0 = fmaf(xv, Ws[k * 128 + lane], acc0);
                acc1 = fmaf(xv, Ws[k * 128 + 64 + lane], acc1);
            }
            h[(size_t)r * 128 + lane] = __float2half(acc0);
            h[(size_t)r * 128 + 64 + lane] = __float2half(acc1);
            float vs0 = acc0 * as0, vs1 = acc1 * as1;
            float vd0 = acc0 * ad0, vd1 = acc1 * ad1;
            #pragma unroll
            for (int off = 16; off >= 1; off >>= 1) {
                vs0 += __shfl_xor(vs0, off, 32);
                vs1 += __shfl_xor(vs1, off, 32);
                vd0 += __shfl_xor(vd0, off, 32);
                vd1 += __shfl_xor(vd1, off, 32);
            }
            if ((lane & 31) == 0) {
                int gg = lane >> 5;
                alsrc[r * 4 + gg] = vs0;     alsrc[r * 4 + 2 + gg] = vs1;
                aldst[r * 4 + gg] = vd0;     aldst[r * 4 + 2 + gg] = vd1;
            }
        }
    }
}

// ---------------- Layer 2 node aggregation + head-mean + bias + ELU + log_softmax ----------------
// One wave per dst node. Quarter-wave edge split; lane owns cols 8c..8c+7 (c = lane & 15),
// head = c >> 2, col block jc = c & 3 (cols 8*jc..8*jc+7 within the 32-wide head).

__global__ __launch_bounds__(256) void node2_k(const __half* __restrict__ h, const float* __restrict__ alsrc,
                                               const float* __restrict__ aldst, const int* __restrict__ rp,
                                               const int* __restrict__ cnt, const int* __restrict__ col,
                                               const float* __restrict__ bias, float* __restrict__ out, int N) {
    int wid = (blockIdx.x * 256 + threadIdx.x) >> 6;
    int lane = threadIdx.x & 63;
    if (wid >= N) return;
    int d = wid;
    int g = lane >> 4;
    int c = lane & 15;
    int head = c >> 2;
    float ad = aldst[d * 4 + head];
    float den = 0.f;
    float a[8] = {0, 0, 0, 0, 0, 0, 0, 0};
    if (g == 0) {  // self loop
        float e0 = alsrc[d * 4 + head] + ad;
        float w = __expf(e0 > 0.f ? e0 : NEG * e0);
        den = w;
        uint4 u = *(const uint4*)(h + (size_t)d * 128 + 8 * c);
        const __half2* hp = (const __half2*)&u;
        #pragma unroll
        for (int j = 0; j < 4; j++) {
            float2 f = __half22float2(hp[j]);
            a[2 * j] = w * f.x; a[2 * j + 1] = w * f.y;
        }
    }
    int start = rp[d], deg = cnt[d];
    for (int i = g; i < deg; i += 4) {
        int s = col[start + i];
        float e = alsrc[s * 4 + head] + ad;
        float w = __expf(e > 0.f ? e : NEG * e);
        den += w;
        uint4 u = *(const uint4*)(h + (size_t)s * 128 + 8 * c);
        const __half2* hp = (const __half2*)&u;
        #pragma unroll
        for (int j = 0; j < 4; j++) {
            float2 f = __half22float2(hp[j]);
            a[2 * j] = fmaf(w, f.x, a[2 * j]);
            a[2 * j + 1] = fmaf(w, f.y, a[2 * j + 1]);
        }
    }
    #pragma unroll
    for (int off = 16; off <= 32; off <<= 1) {
        #pragma unroll
        for (int j = 0; j < 8; j++) a[j] += __shfl_xor(a[j], off);
        den += __shfl_xor(den, off);
    }
    float inv = 1.f / den;
    float v[8];
    #pragma unroll
    for (int j = 0; j < 8; j++) v[j] = a[j] * inv;
    // head-mean: sum across head bits (lane bits of value 4 and 8)
    #pragma unroll
    for (int off = 4; off <= 8; off <<= 1) {
        #pragma unroll
        for (int j = 0; j < 8; j++) v[j] += __shfl_xor(v[j], off);
    }
    int jc = c & 3;
    float ev[8];
    #pragma unroll
    for (int j = 0; j < 8; j++) {
        float val = 0.25f * v[j] + bias[8 * jc + j];
        ev[j] = val > 0.f ? val : expm1f(val);
    }
    float mx = ev[0];
    #pragma unroll
    for (int j = 1; j < 8; j++) mx = fmaxf(mx, ev[j]);
    #pragma unroll
    for (int off = 1; off <= 2; off <<= 1) mx = fmaxf(mx, __shfl_xor(mx, off));
    float sum = 0.f;
    #pragma unroll
    for (int j = 0; j < 8; j++) sum += __expf(ev[j] - mx);
    #pragma unroll
    for (int off = 1; off <= 2; off <<= 1) sum += __shfl_xor(sum, off);
    float ls = mx + __logf(sum);
    if (lane < 4) {
        float4 o0, o1;
        o0.x = ev[0] - ls; o0.y = ev[1] - ls; o0.z = ev[2] - ls; o0.w = ev[3] - ls;
        o1.x = ev[4] - ls; o1.y = ev[5] - ls; o1.z = ev[6] - ls; o1.w = ev[7] - ls;
        *(float4*)(out + (size_t)d * 32 + 8 * jc) = o0;
        *(float4*)(out + (size_t)d * 32 + 8 * jc + 4) = o1;
    }
}

// ---------------- launch ----------------

extern "C" void kernel_launch(void* const* d_in, const int* in_sizes, int n_in,
                              void* d_out, int out_size, void* d_ws, size_t ws_size,
                              hipStream_t stream) {
    const float* x   = (const float*)d_in[0];
    const int*   ei  = (const int*)d_in[1];
    const float* W1  = (const float*)d_in[2];
    const float* as1 = (const float*)d_in[3];
    const float* ad1 = (const float*)d_in[4];
    const float* b1  = (const float*)d_in[5];
    const float* W2  = (const float*)d_in[6];
    const float* as2 = (const float*)d_in[7];
    const float* ad2 = (const float*)d_in[8];
    const float* b2  = (const float*)d_in[9];
    float* out = (float*)d_out;
    int N = in_sizes[0] / 128;
    int E = in_sizes[1] / 2;

    char* base = (char*)d_ws;
    size_t off = 0;
    auto alloc = [&](size_t bytes) -> char* {
        char* p = base + off;
        off = (off + bytes + 255) & ~(size_t)255;
        return p;
    };
    __half* h1h   = (__half*)alloc((size_t)N * 64 * 2);
    __half* h2h   = (__half*)alloc((size_t)N * 128 * 2);
    float* h1o    = (float*)alloc((size_t)N * 64 * 4);
    float* alsrc1 = (float*)alloc((size_t)N * 4 * 4);
    float* aldst1 = (float*)alloc((size_t)N * 4 * 4);
    float* alsrc2 = (float*)alloc((size_t)N * 4 * 4);
    float* aldst2 = (float*)alloc((size_t)N * 4 * 4);
    int* cnt = (int*)alloc((size_t)N * 4);
    int* rp  = (int*)alloc((size_t)N * 4);
    int* cur = (int*)alloc((size_t)N * 4);
    int* bs  = (int*)alloc(1024 * 4);
    int* col = (int*)alloc((size_t)E * 4);

    int nb = (N + 255) / 256;
    hipMemsetAsync(cnt, 0, (size_t)N * 4, stream);
    hipMemsetAsync(cur, 0, (size_t)N * 4, stream);
    hist_k<<<(E + 255) / 256, 256, 0, stream>>>(ei, cnt, E);
    scan1_k<<<nb, 256, 0, stream>>>(cnt, rp, bs, N);
    scan2_k<<<1, 1024, 0, stream>>>(bs, nb);
    scan3_k<<<nb, 256, 0, stream>>>(rp, bs, N);
    scatter_k<<<(E + 255) / 256, 256, 0, stream>>>(ei, rp, cur, col, E);

    gemm1_k<<<1024, 256, 0, stream>>>(x, W1, as1, ad1, h1h, alsrc1, aldst1, N);
    node1_k<<<(N + 3) / 4, 256, 0, stream>>>(h1h, alsrc1, aldst1, rp, cnt, col, b1, h1o, N);
    gemm2_k<<<1024, 256, 0, stream>>>(h1o, W2, as2, ad2, h2h, alsrc2, aldst2, N);
    node2_k<<<(N + 3) / 4, 256, 0, stream>>>(h2h, alsrc2, aldst2, rp, cnt, col, b2, out, N);
}

// Round 3
// 522.203 us; speedup vs baseline: 1.5658x; 1.2182x over previous
//
#include <hip/hip_runtime.h>
#include <hip/hip_fp16.h>
#include <cstdint>
#include <cstddef>

#define NEG 0.2f

// ---------------- CSR build ----------------

__global__ __launch_bounds__(256) void hist_k(const int* __restrict__ ei, int* __restrict__ cnt, int E) {
    int i = blockIdx.x * 256 + threadIdx.x;
    if (i < E) atomicAdd(&cnt[ei[E + i]], 1);
}

__global__ __launch_bounds__(256) void scan1_k(const int* __restrict__ cnt, int* __restrict__ rp,
                                               int* __restrict__ bs, int N) {
    __shared__ int sm[256];
    int t = threadIdx.x, i = blockIdx.x * 256 + t;
    int v = (i < N) ? cnt[i] : 0;
    sm[t] = v; __syncthreads();
    for (int off = 1; off < 256; off <<= 1) {
        int u = (t >= off) ? sm[t - off] : 0;
        __syncthreads();
        sm[t] += u;
        __syncthreads();
    }
    if (i < N) rp[i] = sm[t] - v;          // exclusive within block
    if (t == 255) bs[blockIdx.x] = sm[255];
}

__global__ __launch_bounds__(1024) void scan2_k(int* __restrict__ bs, int nb) {
    __shared__ int sm[1024];
    int t = threadIdx.x;
    int v = (t < nb) ? bs[t] : 0;
    sm[t] = v; __syncthreads();
    for (int off = 1; off < 1024; off <<= 1) {
        int u = (t >= off) ? sm[t - off] : 0;
        __syncthreads();
        sm[t] += u;
        __syncthreads();
    }
    if (t < nb) bs[t] = sm[t] - v;         // exclusive block offsets
}

__global__ __launch_bounds__(256) void scan3_k(int* __restrict__ rp, const int* __restrict__ bs, int N) {
    int i = blockIdx.x * 256 + threadIdx.x;
    if (i < N) rp[i] += bs[blockIdx.x];
}

__global__ __launch_bounds__(256) void scatter_k(const int* __restrict__ ei, const int* __restrict__ rp,
                                                 int* __restrict__ cur, int* __restrict__ col, int E) {
    int i = blockIdx.x * 256 + threadIdx.x;
    if (i < E) {
        int s = ei[i], d = ei[E + i];
        int pos = rp[d] + atomicAdd(&cur[d], 1);
        col[pos] = s;
    }
}

// ---------------- Layer 1 GEMM: h1 = x @ W1 (fp16 out), register-tiled ----------------
// Block: 64-row x 64-col tile. Thread (ct=t&15, rt=t>>4) owns 4 rows x 4 cols.
// W staged once (32 KB); x staged per tile in two K=64 chunks (xs[64][68], pad kills
// write conflicts, stride%4==0 keeps b128 alignment).

__global__ __launch_bounds__(256) void gemm1_k(const float* __restrict__ x, const float* __restrict__ W,
                                               const float* __restrict__ a_src, const float* __restrict__ a_dst,
                                               __half* __restrict__ h, float* __restrict__ alsrc,
                                               float* __restrict__ aldst, int N) {
    __shared__ float Bs[128 * 64];
    __shared__ float xs[64][68];
    int t = threadIdx.x;
    for (int i = t; i < 128 * 64 / 4; i += 256)
        ((float4*)Bs)[i] = ((const float4*)W)[i];
    int ct = t & 15, rt = t >> 4;
    int head = ct >> 2, cq = ct & 3;
    float asv[4], adv[4];
    #pragma unroll
    for (int j = 0; j < 4; j++) {
        asv[j] = a_src[head * 16 + 4 * cq + j];
        adv[j] = a_dst[head * 16 + 4 * cq + j];
    }
    int ntiles = (N + 63) >> 6;
    for (int tile = blockIdx.x; tile < ntiles; tile += gridDim.x) {
        int r0 = tile << 6;
        float acc[4][4];
        #pragma unroll
        for (int i = 0; i < 4; i++)
            #pragma unroll
            for (int j = 0; j < 4; j++) acc[i][j] = 0.f;
        for (int kc = 0; kc < 128; kc += 64) {
            __syncthreads();
            int srow = t >> 4, sf4 = t & 15;
            #pragma unroll
            for (int p = 0; p < 4; p++) {
                int r = r0 + srow + 16 * p;
                float4 v = make_float4(0.f, 0.f, 0.f, 0.f);
                if (r < N) v = *(const float4*)(x + (size_t)r * 128 + kc + 4 * sf4);
                *(float4*)&xs[srow + 16 * p][4 * sf4] = v;
            }
            __syncthreads();
            #pragma unroll 4
            for (int k = 0; k < 64; k++) {
                float4 bv = *(float4*)&Bs[(kc + k) * 64 + 4 * ct];
                #pragma unroll
                for (int i = 0; i < 4; i++) {
                    float xv = xs[4 * rt + i][k];
                    acc[i][0] = fmaf(xv, bv.x, acc[i][0]);
                    acc[i][1] = fmaf(xv, bv.y, acc[i][1]);
                    acc[i][2] = fmaf(xv, bv.z, acc[i][2]);
                    acc[i][3] = fmaf(xv, bv.w, acc[i][3]);
                }
            }
        }
        #pragma unroll
        for (int i = 0; i < 4; i++) {
            int r = r0 + 4 * rt + i;
            float ps = 0.f, pd = 0.f;
            #pragma unroll
            for (int j = 0; j < 4; j++) {
                ps = fmaf(acc[i][j], asv[j], ps);
                pd = fmaf(acc[i][j], adv[j], pd);
            }
            ps += __shfl_xor(ps, 1); ps += __shfl_xor(ps, 2);
            pd += __shfl_xor(pd, 1); pd += __shfl_xor(pd, 2);
            if (r < N) {
                __half2 h0 = __floats2half2_rn(acc[i][0], acc[i][1]);
                __half2 h1 = __floats2half2_rn(acc[i][2], acc[i][3]);
                *(__half2*)(h + (size_t)r * 64 + 4 * ct) = h0;
                *(__half2*)(h + (size_t)r * 64 + 4 * ct + 2) = h1;
                if (cq == 0) { alsrc[r * 4 + head] = ps; aldst[r * 4 + head] = pd; }
            }
        }
    }
}

// ---------------- Layer 1 node aggregation (fp16 packed accumulate) ----------------
// One wave per dst node; quarter-wave g handles edges i = g, g+4, ...; lane owns 4 cols.

__global__ __launch_bounds__(256) void node1_k(const __half* __restrict__ h, const float* __restrict__ alsrc,
                                               const float* __restrict__ aldst, const int* __restrict__ rp,
                                               const int* __restrict__ cnt, const int* __restrict__ col,
                                               const float* __restrict__ bias, __half* __restrict__ out, int N) {
    int wid = (blockIdx.x * 256 + threadIdx.x) >> 6;
    int lane = threadIdx.x & 63;
    if (wid >= N) return;
    int d = wid;
    int g = lane >> 4;
    int c = lane & 15;
    int head = c >> 2;
    float ad = aldst[d * 4 + head];
    float den = 0.f;
    __half2 acc0 = __float2half2_rn(0.f), acc1 = __float2half2_rn(0.f);
    const __half2* hb = (const __half2*)h;
    unsigned co = 2u * c;
    if (g == 0) {  // self loop
        float e0 = alsrc[d * 4 + head] + ad;
        float w = __expf(e0 > 0.f ? e0 : NEG * e0);
        den = w;
        __half2 w2 = __float2half2_rn(w);
        uint2 u = *(const uint2*)(hb + ((unsigned)d << 5) + co);
        acc0 = __hfma2(w2, *(__half2*)&u.x, acc0);
        acc1 = __hfma2(w2, *(__half2*)&u.y, acc1);
    }
    int start = rp[d], deg = cnt[d];
    for (int i = g; i < deg; i += 4) {
        int s = col[start + i];
        float e = alsrc[s * 4 + head] + ad;
        float w = __expf(e > 0.f ? e : NEG * e);
        den += w;
        __half2 w2 = __float2half2_rn(w);
        uint2 u = *(const uint2*)(hb + ((unsigned)s << 5) + co);
        acc0 = __hfma2(w2, *(__half2*)&u.x, acc0);
        acc1 = __hfma2(w2, *(__half2*)&u.y, acc1);
    }
    float2 f0 = __half22float2(acc0), f1 = __half22float2(acc1);
    float a0 = f0.x, a1 = f0.y, a2 = f1.x, a3 = f1.y;
    #pragma unroll
    for (int off = 16; off <= 32; off <<= 1) {
        a0 += __shfl_xor(a0, off); a1 += __shfl_xor(a1, off);
        a2 += __shfl_xor(a2, off); a3 += __shfl_xor(a3, off);
        den += __shfl_xor(den, off);
    }
    if (lane < 16) {
        float inv = 1.f / den;
        float4 b = *(const float4*)(bias + 4 * c);
        __half2 o0 = __floats2half2_rn(a0 * inv + b.x, a1 * inv + b.y);
        __half2 o1 = __floats2half2_rn(a2 * inv + b.z, a3 * inv + b.w);
        uint2 o; o.x = *(unsigned*)&o0; o.y = *(unsigned*)&o1;
        *(uint2*)(out + (size_t)d * 64 + 4 * c) = o;
    }
}

// ---------------- Layer 2 GEMM: h2 = h1o(fp16) @ W2 (fp16 out), register-tiled ----------------
// Thread owns 4 rows x (cols 4ct and 64+4ct). Both col blocks land in one head each.

__global__ __launch_bounds__(256) void gemm2_k(const __half* __restrict__ xh, const float* __restrict__ W,
                                               const float* __restrict__ a_src, const float* __restrict__ a_dst,
                                               __half* __restrict__ h, float* __restrict__ alsrc,
                                               float* __restrict__ aldst, int N) {
    __shared__ float Bs[64 * 128];
    __shared__ float xs[64][68];
    int t = threadIdx.x;
    for (int i = t; i < 64 * 128 / 4; i += 256)
        ((float4*)Bs)[i] = ((const float4*)W)[i];
    int ct = t & 15, rt = t >> 4;
    int hA = ct >> 3, cq = ct & 7;
    float asA[4], adA[4], asB[4], adB[4];
    #pragma unroll
    for (int j = 0; j < 4; j++) {
        asA[j] = a_src[hA * 32 + 4 * cq + j];
        adA[j] = a_dst[hA * 32 + 4 * cq + j];
        asB[j] = a_src[(2 + hA) * 32 + 4 * cq + j];
        adB[j] = a_dst[(2 + hA) * 32 + 4 * cq + j];
    }
    int ntiles = (N + 63) >> 6;
    for (int tile = blockIdx.x; tile < ntiles; tile += gridDim.x) {
        int r0 = tile << 6;
        float accA[4][4], accB[4][4];
        #pragma unroll
        for (int i = 0; i < 4; i++)
            #pragma unroll
            for (int j = 0; j < 4; j++) { accA[i][j] = 0.f; accB[i][j] = 0.f; }
        __syncthreads();
        int srow = t >> 3, su = t & 7;
        #pragma unroll
        for (int p = 0; p < 2; p++) {
            int r = r0 + srow + 32 * p;
            float2 g0 = make_float2(0.f, 0.f), g1 = g0, g2 = g0, g3 = g0;
            if (r < N) {
                uint4 u = *(const uint4*)(xh + (size_t)r * 64 + 8 * su);
                const __half2* hp = (const __half2*)&u;
                g0 = __half22float2(hp[0]); g1 = __half22float2(hp[1]);
                g2 = __half22float2(hp[2]); g3 = __half22float2(hp[3]);
            }
            *(float4*)&xs[srow + 32 * p][8 * su] = make_float4(g0.x, g0.y, g1.x, g1.y);
            *(float4*)&xs[srow + 32 * p][8 * su + 4] = make_float4(g2.x, g2.y, g3.x, g3.y);
        }
        __syncthreads();
        #pragma unroll 4
        for (int k = 0; k < 64; k++) {
            float4 bA = *(float4*)&Bs[k * 128 + 4 * ct];
            float4 bB = *(float4*)&Bs[k * 128 + 64 + 4 * ct];
            #pragma unroll
            for (int i = 0; i < 4; i++) {
                float xv = xs[4 * rt + i][k];
                accA[i][0] = fmaf(xv, bA.x, accA[i][0]);
                accA[i][1] = fmaf(xv, bA.y, accA[i][1]);
                accA[i][2] = fmaf(xv, bA.z, accA[i][2]);
                accA[i][3] = fmaf(xv, bA.w, accA[i][3]);
                accB[i][0] = fmaf(xv, bB.x, accB[i][0]);
                accB[i][1] = fmaf(xv, bB.y, accB[i][1]);
                accB[i][2] = fmaf(xv, bB.z, accB[i][2]);
                accB[i][3] = fmaf(xv, bB.w, accB[i][3]);
            }
        }
        #pragma unroll
        for (int i = 0; i < 4; i++) {
            int r = r0 + 4 * rt + i;
            float psA = 0.f, pdA = 0.f, psB = 0.f, pdB = 0.f;
            #pragma unroll
            for (int j = 0; j < 4; j++) {
                psA = fmaf(accA[i][j], asA[j], psA);
                pdA = fmaf(accA[i][j], adA[j], pdA);
                psB = fmaf(accB[i][j], asB[j], psB);
                pdB = fmaf(accB[i][j], adB[j], pdB);
            }
            #pragma unroll
            for (int off = 1; off <= 4; off <<= 1) {
                psA += __shfl_xor(psA, off); pdA += __shfl_xor(pdA, off);
                psB += __shfl_xor(psB, off); pdB += __shfl_xor(pdB, off);
            }
            if (r < N) {
                __half2 hA0 = __floats2half2_rn(accA[i][0], accA[i][1]);
                __half2 hA1 = __floats2half2_rn(accA[i][2], accA[i][3]);
                __half2 hB0 = __floats2half2_rn(accB[i][0], accB[i][1]);
                __half2 hB1 = __floats2half2_rn(accB[i][2], accB[i][3]);
                *(__half2*)(h + (size_t)r * 128 + 4 * ct) = hA0;
                *(__half2*)(h + (size_t)r * 128 + 4 * ct + 2) = hA1;
                *(__half2*)(h + (size_t)r * 128 + 64 + 4 * ct) = hB0;
                *(__half2*)(h + (size_t)r * 128 + 64 + 4 * ct + 2) = hB1;
                if (cq == 0) {
                    alsrc[r * 4 + hA] = psA;     alsrc[r * 4 + 2 + hA] = psB;
                    aldst[r * 4 + hA] = pdA;     aldst[r * 4 + 2 + hA] = pdB;
                }
            }
        }
    }
}

// ---------------- Layer 2 node aggregation + head-mean + bias + ELU + log_softmax ----------------

__global__ __launch_bounds__(256) void node2_k(const __half* __restrict__ h, const float* __restrict__ alsrc,
                                               const float* __restrict__ aldst, const int* __restrict__ rp,
                                               const int* __restrict__ cnt, const int* __restrict__ col,
                                               const float* __restrict__ bias, float* __restrict__ out, int N) {
    int wid = (blockIdx.x * 256 + threadIdx.x) >> 6;
    int lane = threadIdx.x & 63;
    if (wid >= N) return;
    int d = wid;
    int g = lane >> 4;
    int c = lane & 15;
    int head = c >> 2;
    float ad = aldst[d * 4 + head];
    float den = 0.f;
    __half2 acc[4];
    #pragma unroll
    for (int j = 0; j < 4; j++) acc[j] = __float2half2_rn(0.f);
    const __half2* hb = (const __half2*)h;
    unsigned co = 4u * c;
    if (g == 0) {  // self loop
        float e0 = alsrc[d * 4 + head] + ad;
        float w = __expf(e0 > 0.f ? e0 : NEG * e0);
        den = w;
        __half2 w2 = __float2half2_rn(w);
        uint4 u = *(const uint4*)(hb + ((unsigned)d << 6) + co);
        const __half2* hp = (const __half2*)&u;
        #pragma unroll
        for (int j = 0; j < 4; j++) acc[j] = __hfma2(w2, hp[j], acc[j]);
    }
    int start = rp[d], deg = cnt[d];
    for (int i = g; i < deg; i += 4) {
        int s = col[start + i];
        float e = alsrc[s * 4 + head] + ad;
        float w = __expf(e > 0.f ? e : NEG * e);
        den += w;
        __half2 w2 = __float2half2_rn(w);
        uint4 u = *(const uint4*)(hb + ((unsigned)s << 6) + co);
        const __half2* hp = (const __half2*)&u;
        #pragma unroll
        for (int j = 0; j < 4; j++) acc[j] = __hfma2(w2, hp[j], acc[j]);
    }
    float a[8];
    #pragma unroll
    for (int j = 0; j < 4; j++) {
        float2 f = __half22float2(acc[j]);
        a[2 * j] = f.x; a[2 * j + 1] = f.y;
    }
    #pragma unroll
    for (int off = 16; off <= 32; off <<= 1) {
        #pragma unroll
        for (int j = 0; j < 8; j++) a[j] += __shfl_xor(a[j], off);
        den += __shfl_xor(den, off);
    }
    float inv = 1.f / den;
    float v[8];
    #pragma unroll
    for (int j = 0; j < 8; j++) v[j] = a[j] * inv;
    #pragma unroll
    for (int off = 4; off <= 8; off <<= 1) {
        #pragma unroll
        for (int j = 0; j < 8; j++) v[j] += __shfl_xor(v[j], off);
    }
    int jc = c & 3;
    float ev[8];
    #pragma unroll
    for (int j = 0; j < 8; j++) {
        float val = 0.25f * v[j] + bias[8 * jc + j];
        ev[j] = val > 0.f ? val : expm1f(val);
    }
    float mx = ev[0];
    #pragma unroll
    for (int j = 1; j < 8; j++) mx = fmaxf(mx, ev[j]);
    #pragma unroll
    for (int off = 1; off <= 2; off <<= 1) mx = fmaxf(mx, __shfl_xor(mx, off));
    float sum = 0.f;
    #pragma unroll
    for (int j = 0; j < 8; j++) sum += __expf(ev[j] - mx);
    #pragma unroll
    for (int off = 1; off <= 2; off <<= 1) sum += __shfl_xor(sum, off);
    float ls = mx + __logf(sum);
    if (lane < 4) {
        float4 o0, o1;
        o0.x = ev[0] - ls; o0.y = ev[1] - ls; o0.z = ev[2] - ls; o0.w = ev[3] - ls;
        o1.x = ev[4] - ls; o1.y = ev[5] - ls; o1.z = ev[6] - ls; o1.w = ev[7] - ls;
        *(float4*)(out + (size_t)d * 32 + 8 * jc) = o0;
        *(float4*)(out + (size_t)d * 32 + 8 * jc + 4) = o1;
    }
}

// ---------------- launch ----------------

extern "C" void kernel_launch(void* const* d_in, const int* in_sizes, int n_in,
                              void* d_out, int out_size, void* d_ws, size_t ws_size,
                              hipStream_t stream) {
    const float* x   = (const float*)d_in[0];
    const int*   ei  = (const int*)d_in[1];
    const float* W1  = (const float*)d_in[2];
    const float* as1 = (const float*)d_in[3];
    const float* ad1 = (const float*)d_in[4];
    const float* b1  = (const float*)d_in[5];
    const float* W2  = (const float*)d_in[6];
    const float* as2 = (const float*)d_in[7];
    const float* ad2 = (const float*)d_in[8];
    const float* b2  = (const float*)d_in[9];
    float* out = (float*)d_out;
    int N = in_sizes[0] / 128;
    int E = in_sizes[1] / 2;

    char* base = (char*)d_ws;
    size_t off = 0;
    auto alloc = [&](size_t bytes) -> char* {
        char* p = base + off;
        off = (off + bytes + 255) & ~(size_t)255;
        return p;
    };
    __half* h1h   = (__half*)alloc((size_t)N * 64 * 2);
    __half* h2h   = (__half*)alloc((size_t)N * 128 * 2);
    __half* h1o   = (__half*)alloc((size_t)N * 64 * 2);
    float* alsrc1 = (float*)alloc((size_t)N * 4 * 4);
    float* aldst1 = (float*)alloc((size_t)N * 4 * 4);
    float* alsrc2 = (float*)alloc((size_t)N * 4 * 4);
    float* aldst2 = (float*)alloc((size_t)N * 4 * 4);
    int* cnt = (int*)alloc((size_t)N * 4);
    int* rp  = (int*)alloc((size_t)N * 4);
    int* cur = (int*)alloc((size_t)N * 4);
    int* bs  = (int*)alloc(1024 * 4);
    int* col = (int*)alloc((size_t)E * 4);

    int nb = (N + 255) / 256;
    hipMemsetAsync(cnt, 0, (size_t)N * 4, stream);
    hipMemsetAsync(cur, 0, (size_t)N * 4, stream);
    hist_k<<<(E + 255) / 256, 256, 0, stream>>>(ei, cnt, E);
    scan1_k<<<nb, 256, 0, stream>>>(cnt, rp, bs, N);
    scan2_k<<<1, 1024, 0, stream>>>(bs, nb);
    scan3_k<<<nb, 256, 0, stream>>>(rp, bs, N);
    scatter_k<<<(E + 255) / 256, 256, 0, stream>>>(ei, rp, cur, col, E);

    gemm1_k<<<768, 256, 0, stream>>>(x, W1, as1, ad1, h1h, alsrc1, aldst1, N);
    node1_k<<<(N + 3) / 4, 256, 0, stream>>>(h1h, alsrc1, aldst1, rp, cnt, col, b1, h1o, N);
    gemm2_k<<<768, 256, 0, stream>>>(h1o, W2, as2, ad2, h2h, alsrc2, aldst2, N);
    node2_k<<<(N + 3) / 4, 256, 0, stream>>>(h2h, alsrc2, aldst2, rp, cnt, col, b2, out, N);
}

// Round 4
// 519.461 us; speedup vs baseline: 1.5741x; 1.0053x over previous
//
#include <hip/hip_runtime.h>
#include <hip/hip_fp16.h>
#include <cstdint>
#include <cstddef>

#define NEG 0.2f
#define SCS 4096   // scatter chunk size (edges)

// ---------------- CSR build ----------------

__global__ __launch_bounds__(256) void hist_k(const int* __restrict__ ei, int* __restrict__ cnt, int E) {
    int i = blockIdx.x * 256 + threadIdx.x;
    if (i < E) atomicAdd(&cnt[ei[E + i]], 1);
}

__global__ __launch_bounds__(256) void scan1_k(const int* __restrict__ cnt, int* __restrict__ rp,
                                               int* __restrict__ bs, int N) {
    __shared__ int sm[256];
    int t = threadIdx.x, i = blockIdx.x * 256 + t;
    int v = (i < N) ? cnt[i] : 0;
    sm[t] = v; __syncthreads();
    for (int off = 1; off < 256; off <<= 1) {
        int u = (t >= off) ? sm[t - off] : 0;
        __syncthreads();
        sm[t] += u;
        __syncthreads();
    }
    if (i < N) rp[i] = sm[t] - v;          // exclusive within block
    if (t == 255) bs[blockIdx.x] = sm[255];
}

__global__ __launch_bounds__(1024) void scan2_k(int* __restrict__ bs, int nb) {
    __shared__ int sm[1024];
    int t = threadIdx.x;
    int v = (t < nb) ? bs[t] : 0;
    sm[t] = v; __syncthreads();
    for (int off = 1; off < 1024; off <<= 1) {
        int u = (t >= off) ? sm[t - off] : 0;
        __syncthreads();
        sm[t] += u;
        __syncthreads();
    }
    if (t < nb) bs[t] = sm[t] - v;         // exclusive block offsets
}

__global__ __launch_bounds__(256) void scan3_k(int* __restrict__ rp, const int* __restrict__ bs, int N) {
    int i = blockIdx.x * 256 + threadIdx.x;
    if (i < N) rp[i] += bs[blockIdx.x];
}

// XCD-pinned scatter: persistent blocks; each block steals 4096-edge chunks from its
// own XCD's queue and handles only edges whose dst is in partition == XCC_ID.
// All writes to a given col cache line then come from ONE XCD's L2 -> line fills
// fully and evicts once (kills the 16x partial-line write amplification).
__global__ __launch_bounds__(256) void scatter_pin_k(const int* __restrict__ ei, const int* __restrict__ rp,
                                                     int* __restrict__ cur, int* __restrict__ col,
                                                     int* __restrict__ q, int E, int nchunks, unsigned M) {
    __shared__ int smc;
    int xcd = __builtin_amdgcn_s_getreg(6164) & 7;   // hwreg(HW_REG_XCC_ID=20, off 0, sz 4)
    for (;;) {
        if (threadIdx.x == 0) smc = atomicAdd(&q[xcd], 1);
        __syncthreads();
        int c = smc;
        __syncthreads();
        if (c >= nchunks) return;
        int hi = min(c * SCS + SCS, E);
        for (int i = c * SCS + threadIdx.x; i < hi; i += 256) {
            int d = ei[E + i];
            int part = (int)(((unsigned long long)(unsigned)d * M) >> 35);
            if (part == xcd) {
                int s = ei[i];
                int pos = rp[d] + atomicAdd(&cur[d], 1);
                col[pos] = s;
            }
        }
    }
}

// Safety net: drains whatever chunks scatter_pin_k left unclaimed (e.g. if some
// XCD received no blocks). Chunk claims are exactly-once via the same atomics,
// so this is a no-op when the pinned kernel covered everything.
__global__ __launch_bounds__(256) void scatter_fix_k(const int* __restrict__ ei, const int* __restrict__ rp,
                                                     int* __restrict__ cur, int* __restrict__ col,
                                                     int* __restrict__ q, int E, int nchunks, unsigned M) {
    __shared__ int smc;
    for (int p = 0; p < 8; p++) {
        for (;;) {
            if (threadIdx.x == 0) smc = atomicAdd(&q[p], 1);
            __syncthreads();
            int c = smc;
            __syncthreads();
            if (c >= nchunks) break;
            int hi = min(c * SCS + SCS, E);
            for (int i = c * SCS + threadIdx.x; i < hi; i += 256) {
                int d = ei[E + i];
                int part = (int)(((unsigned long long)(unsigned)d * M) >> 35);
                if (part == p) {
                    int s = ei[i];
                    int pos = rp[d] + atomicAdd(&cur[d], 1);
                    col[pos] = s;
                }
            }
        }
    }
}

// ---------------- Layer 1 GEMM: h1 = x @ W1 (fp16 out), register-tiled ----------------

__global__ __launch_bounds__(256) void gemm1_k(const float* __restrict__ x, const float* __restrict__ W,
                                               const float* __restrict__ a_src, const float* __restrict__ a_dst,
                                               __half* __restrict__ h, float* __restrict__ alsrc,
                                               float* __restrict__ aldst, int N) {
    __shared__ float Bs[128 * 64];
    __shared__ float xs[64][68];
    int t = threadIdx.x;
    for (int i = t; i < 128 * 64 / 4; i += 256)
        ((float4*)Bs)[i] = ((const float4*)W)[i];
    int ct = t & 15, rt = t >> 4;
    int head = ct >> 2, cq = ct & 3;
    float asv[4], adv[4];
    #pragma unroll
    for (int j = 0; j < 4; j++) {
        asv[j] = a_src[head * 16 + 4 * cq + j];
        adv[j] = a_dst[head * 16 + 4 * cq + j];
    }
    int ntiles = (N + 63) >> 6;
    for (int tile = blockIdx.x; tile < ntiles; tile += gridDim.x) {
        int r0 = tile << 6;
        float acc[4][4];
        #pragma unroll
        for (int i = 0; i < 4; i++)
            #pragma unroll
            for (int j = 0; j < 4; j++) acc[i][j] = 0.f;
        for (int kc = 0; kc < 128; kc += 64) {
            __syncthreads();
            int srow = t >> 4, sf4 = t & 15;
            #pragma unroll
            for (int p = 0; p < 4; p++) {
                int r = r0 + srow + 16 * p;
                float4 v = make_float4(0.f, 0.f, 0.f, 0.f);
                if (r < N) v = *(const float4*)(x + (size_t)r * 128 + kc + 4 * sf4);
                *(float4*)&xs[srow + 16 * p][4 * sf4] = v;
            }
            __syncthreads();
            #pragma unroll 4
            for (int k = 0; k < 64; k++) {
                float4 bv = *(float4*)&Bs[(kc + k) * 64 + 4 * ct];
                #pragma unroll
                for (int i = 0; i < 4; i++) {
                    float xv = xs[4 * rt + i][k];
                    acc[i][0] = fmaf(xv, bv.x, acc[i][0]);
                    acc[i][1] = fmaf(xv, bv.y, acc[i][1]);
                    acc[i][2] = fmaf(xv, bv.z, acc[i][2]);
                    acc[i][3] = fmaf(xv, bv.w, acc[i][3]);
                }
            }
        }
        #pragma unroll
        for (int i = 0; i < 4; i++) {
            int r = r0 + 4 * rt + i;
            float ps = 0.f, pd = 0.f;
            #pragma unroll
            for (int j = 0; j < 4; j++) {
                ps = fmaf(acc[i][j], asv[j], ps);
                pd = fmaf(acc[i][j], adv[j], pd);
            }
            ps += __shfl_xor(ps, 1); ps += __shfl_xor(ps, 2);
            pd += __shfl_xor(pd, 1); pd += __shfl_xor(pd, 2);
            if (r < N) {
                __half2 h0 = __floats2half2_rn(acc[i][0], acc[i][1]);
                __half2 h1 = __floats2half2_rn(acc[i][2], acc[i][3]);
                *(__half2*)(h + (size_t)r * 64 + 4 * ct) = h0;
                *(__half2*)(h + (size_t)r * 64 + 4 * ct + 2) = h1;
                if (cq == 0) { alsrc[r * 4 + head] = ps; aldst[r * 4 + head] = pd; }
            }
        }
    }
}

// ---------------- Layer 1 node aggregation (fp16 packed accumulate) ----------------

__global__ __launch_bounds__(256) void node1_k(const __half* __restrict__ h, const float* __restrict__ alsrc,
                                               const float* __restrict__ aldst, const int* __restrict__ rp,
                                               const int* __restrict__ cnt, const int* __restrict__ col,
                                               const float* __restrict__ bias, __half* __restrict__ out, int N) {
    int wid = (blockIdx.x * 256 + threadIdx.x) >> 6;
    int lane = threadIdx.x & 63;
    if (wid >= N) return;
    int d = wid;
    int g = lane >> 4;
    int c = lane & 15;
    int head = c >> 2;
    float ad = aldst[d * 4 + head];
    float den = 0.f;
    __half2 acc0 = __float2half2_rn(0.f), acc1 = __float2half2_rn(0.f);
    const __half2* hb = (const __half2*)h;
    unsigned co = 2u * c;
    if (g == 0) {  // self loop
        float e0 = alsrc[d * 4 + head] + ad;
        float w = __expf(e0 > 0.f ? e0 : NEG * e0);
        den = w;
        __half2 w2 = __float2half2_rn(w);
        uint2 u = *(const uint2*)(hb + ((unsigned)d << 5) + co);
        acc0 = __hfma2(w2, *(__half2*)&u.x, acc0);
        acc1 = __hfma2(w2, *(__half2*)&u.y, acc1);
    }
    int start = rp[d], deg = cnt[d];
    for (int i = g; i < deg; i += 4) {
        int s = col[start + i];
        float e = alsrc[s * 4 + head] + ad;
        float w = __expf(e > 0.f ? e : NEG * e);
        den += w;
        __half2 w2 = __float2half2_rn(w);
        uint2 u = *(const uint2*)(hb + ((unsigned)s << 5) + co);
        acc0 = __hfma2(w2, *(__half2*)&u.x, acc0);
        acc1 = __hfma2(w2, *(__half2*)&u.y, acc1);
    }
    float2 f0 = __half22float2(acc0), f1 = __half22float2(acc1);
    float a0 = f0.x, a1 = f0.y, a2 = f1.x, a3 = f1.y;
    #pragma unroll
    for (int off = 16; off <= 32; off <<= 1) {
        a0 += __shfl_xor(a0, off); a1 += __shfl_xor(a1, off);
        a2 += __shfl_xor(a2, off); a3 += __shfl_xor(a3, off);
        den += __shfl_xor(den, off);
    }
    if (lane < 16) {
        float inv = 1.f / den;
        float4 b = *(const float4*)(bias + 4 * c);
        __half2 o0 = __floats2half2_rn(a0 * inv + b.x, a1 * inv + b.y);
        __half2 o1 = __floats2half2_rn(a2 * inv + b.z, a3 * inv + b.w);
        uint2 o; o.x = *(unsigned*)&o0; o.y = *(unsigned*)&o1;
        *(uint2*)(out + (size_t)d * 64 + 4 * c) = o;
    }
}

// ---------------- Layer 2 GEMM: h2 = h1o(fp16) @ W2 (fp16 out), register-tiled ----------------

__global__ __launch_bounds__(256) void gemm2_k(const __half* __restrict__ xh, const float* __restrict__ W,
                                               const float* __restrict__ a_src, const float* __restrict__ a_dst,
                                               __half* __restrict__ h, float* __restrict__ alsrc,
                                               float* __restrict__ aldst, int N) {
    __shared__ float Bs[64 * 128];
    __shared__ float xs[64][68];
    int t = threadIdx.x;
    for (int i = t; i < 64 * 128 / 4; i += 256)
        ((float4*)Bs)[i] = ((const float4*)W)[i];
    int ct = t & 15, rt = t >> 4;
    int hA = ct >> 3, cq = ct & 7;
    float asA[4], adA[4], asB[4], adB[4];
    #pragma unroll
    for (int j = 0; j < 4; j++) {
        asA[j] = a_src[hA * 32 + 4 * cq + j];
        adA[j] = a_dst[hA * 32 + 4 * cq + j];
        asB[j] = a_src[(2 + hA) * 32 + 4 * cq + j];
        adB[j] = a_dst[(2 + hA) * 32 + 4 * cq + j];
    }
    int ntiles = (N + 63) >> 6;
    for (int tile = blockIdx.x; tile < ntiles; tile += gridDim.x) {
        int r0 = tile << 6;
        float accA[4][4], accB[4][4];
        #pragma unroll
        for (int i = 0; i < 4; i++)
            #pragma unroll
            for (int j = 0; j < 4; j++) { accA[i][j] = 0.f; accB[i][j] = 0.f; }
        __syncthreads();
        int srow = t >> 3, su = t & 7;
        #pragma unroll
        for (int p = 0; p < 2; p++) {
            int r = r0 + srow + 32 * p;
            float2 g0 = make_float2(0.f, 0.f), g1 = g0, g2 = g0, g3 = g0;
            if (r < N) {
                uint4 u = *(const uint4*)(xh + (size_t)r * 64 + 8 * su);
                const __half2* hp = (const __half2*)&u;
                g0 = __half22float2(hp[0]); g1 = __half22float2(hp[1]);
                g2 = __half22float2(hp[2]); g3 = __half22float2(hp[3]);
            }
            *(float4*)&xs[srow + 32 * p][8 * su] = make_float4(g0.x, g0.y, g1.x, g1.y);
            *(float4*)&xs[srow + 32 * p][8 * su + 4] = make_float4(g2.x, g2.y, g3.x, g3.y);
        }
        __syncthreads();
        #pragma unroll 4
        for (int k = 0; k < 64; k++) {
            float4 bA = *(float4*)&Bs[k * 128 + 4 * ct];
            float4 bB = *(float4*)&Bs[k * 128 + 64 + 4 * ct];
            #pragma unroll
            for (int i = 0; i < 4; i++) {
                float xv = xs[4 * rt + i][k];
                accA[i][0] = fmaf(xv, bA.x, accA[i][0]);
                accA[i][1] = fmaf(xv, bA.y, accA[i][1]);
                accA[i][2] = fmaf(xv, bA.z, accA[i][2]);
                accA[i][3] = fmaf(xv, bA.w, accA[i][3]);
                accB[i][0] = fmaf(xv, bB.x, accB[i][0]);
                accB[i][1] = fmaf(xv, bB.y, accB[i][1]);
                accB[i][2] = fmaf(xv, bB.z, accB[i][2]);
                accB[i][3] = fmaf(xv, bB.w, accB[i][3]);
            }
        }
        #pragma unroll
        for (int i = 0; i < 4; i++) {
            int r = r0 + 4 * rt + i;
            float psA = 0.f, pdA = 0.f, psB = 0.f, pdB = 0.f;
            #pragma unroll
            for (int j = 0; j < 4; j++) {
                psA = fmaf(accA[i][j], asA[j], psA);
                pdA = fmaf(accA[i][j], adA[j], pdA);
                psB = fmaf(accB[i][j], asB[j], psB);
                pdB = fmaf(accB[i][j], adB[j], pdB);
            }
            #pragma unroll
            for (int off = 1; off <= 4; off <<= 1) {
                psA += __shfl_xor(psA, off); pdA += __shfl_xor(pdA, off);
                psB += __shfl_xor(psB, off); pdB += __shfl_xor(pdB, off);
            }
            if (r < N) {
                __half2 hA0 = __floats2half2_rn(accA[i][0], accA[i][1]);
                __half2 hA1 = __floats2half2_rn(accA[i][2], accA[i][3]);
                __half2 hB0 = __floats2half2_rn(accB[i][0], accB[i][1]);
                __half2 hB1 = __floats2half2_rn(accB[i][2], accB[i][3]);
                *(__half2*)(h + (size_t)r * 128 + 4 * ct) = hA0;
                *(__half2*)(h + (size_t)r * 128 + 4 * ct + 2) = hA1;
                *(__half2*)(h + (size_t)r * 128 + 64 + 4 * ct) = hB0;
                *(__half2*)(h + (size_t)r * 128 + 64 + 4 * ct + 2) = hB1;
                if (cq == 0) {
                    alsrc[r * 4 + hA] = psA;     alsrc[r * 4 + 2 + hA] = psB;
                    aldst[r * 4 + hA] = pdA;     aldst[r * 4 + 2 + hA] = pdB;
                }
            }
        }
    }
}

// ---------------- Layer 2 node aggregation + head-mean + bias + ELU + log_softmax ----------------

__global__ __launch_bounds__(256) void node2_k(const __half* __restrict__ h, const float* __restrict__ alsrc,
                                               const float* __restrict__ aldst, const int* __restrict__ rp,
                                               const int* __restrict__ cnt, const int* __restrict__ col,
                                               const float* __restrict__ bias, float* __restrict__ out, int N) {
    int wid = (blockIdx.x * 256 + threadIdx.x) >> 6;
    int lane = threadIdx.x & 63;
    if (wid >= N) return;
    int d = wid;
    int g = lane >> 4;
    int c = lane & 15;
    int head = c >> 2;
    float ad = aldst[d * 4 + head];
    float den = 0.f;
    __half2 acc[4];
    #pragma unroll
    for (int j = 0; j < 4; j++) acc[j] = __float2half2_rn(0.f);
    const __half2* hb = (const __half2*)h;
    unsigned co = 4u * c;
    if (g == 0) {  // self loop
        float e0 = alsrc[d * 4 + head] + ad;
        float w = __expf(e0 > 0.f ? e0 : NEG * e0);
        den = w;
        __half2 w2 = __float2half2_rn(w);
        uint4 u = *(const uint4*)(hb + ((unsigned)d << 6) + co);
        const __half2* hp = (const __half2*)&u;
        #pragma unroll
        for (int j = 0; j < 4; j++) acc[j] = __hfma2(w2, hp[j], acc[j]);
    }
    int start = rp[d], deg = cnt[d];
    for (int i = g; i < deg; i += 4) {
        int s = col[start + i];
        float e = alsrc[s * 4 + head] + ad;
        float w = __expf(e > 0.f ? e : NEG * e);
        den += w;
        __half2 w2 = __float2half2_rn(w);
        uint4 u = *(const uint4*)(hb + ((unsigned)s << 6) + co);
        const __half2* hp = (const __half2*)&u;
        #pragma unroll
        for (int j = 0; j < 4; j++) acc[j] = __hfma2(w2, hp[j], acc[j]);
    }
    float a[8];
    #pragma unroll
    for (int j = 0; j < 4; j++) {
        float2 f = __half22float2(acc[j]);
        a[2 * j] = f.x; a[2 * j + 1] = f.y;
    }
    #pragma unroll
    for (int off = 16; off <= 32; off <<= 1) {
        #pragma unroll
        for (int j = 0; j < 8; j++) a[j] += __shfl_xor(a[j], off);
        den += __shfl_xor(den, off);
    }
    float inv = 1.f / den;
    float v[8];
    #pragma unroll
    for (int j = 0; j < 8; j++) v[j] = a[j] * inv;
    #pragma unroll
    for (int off = 4; off <= 8; off <<= 1) {
        #pragma unroll
        for (int j = 0; j < 8; j++) v[j] += __shfl_xor(v[j], off);
    }
    int jc = c & 3;
    float ev[8];
    #pragma unroll
    for (int j = 0; j < 8; j++) {
        float val = 0.25f * v[j] + bias[8 * jc + j];
        ev[j] = val > 0.f ? val : expm1f(val);
    }
    float mx = ev[0];
    #pragma unroll
    for (int j = 1; j < 8; j++) mx = fmaxf(mx, ev[j]);
    #pragma unroll
    for (int off = 1; off <= 2; off <<= 1) mx = fmaxf(mx, __shfl_xor(mx, off));
    float sum = 0.f;
    #pragma unroll
    for (int j = 0; j < 8; j++) sum += __expf(ev[j] - mx);
    #pragma unroll
    for (int off = 1; off <= 2; off <<= 1) sum += __shfl_xor(sum, off);
    float ls = mx + __logf(sum);
    if (lane < 4) {
        float4 o0, o1;
        o0.x = ev[0] - ls; o0.y = ev[1] - ls; o0.z = ev[2] - ls; o0.w = ev[3] - ls;
        o1.x = ev[4] - ls; o1.y = ev[5] - ls; o1.z = ev[6] - ls; o1.w = ev[7] - ls;
        *(float4*)(out + (size_t)d * 32 + 8 * jc) = o0;
        *(float4*)(out + (size_t)d * 32 + 8 * jc + 4) = o1;
    }
}

// ---------------- launch ----------------

extern "C" void kernel_launch(void* const* d_in, const int* in_sizes, int n_in,
                              void* d_out, int out_size, void* d_ws, size_t ws_size,
                              hipStream_t stream) {
    const float* x   = (const float*)d_in[0];
    const int*   ei  = (const int*)d_in[1];
    const float* W1  = (const float*)d_in[2];
    const float* as1 = (const float*)d_in[3];
    const float* ad1 = (const float*)d_in[4];
    const float* b1  = (const float*)d_in[5];
    const float* W2  = (const float*)d_in[6];
    const float* as2 = (const float*)d_in[7];
    const float* ad2 = (const float*)d_in[8];
    const float* b2  = (const float*)d_in[9];
    float* out = (float*)d_out;
    int N = in_sizes[0] / 128;
    int E = in_sizes[1] / 2;

    char* base = (char*)d_ws;
    size_t off = 0;
    auto alloc = [&](size_t bytes) -> char* {
        char* p = base + off;
        off = (off + bytes + 255) & ~(size_t)255;
        return p;
    };
    __half* h1h   = (__half*)alloc((size_t)N * 64 * 2);
    __half* h2h   = (__half*)alloc((size_t)N * 128 * 2);
    __half* h1o   = (__half*)alloc((size_t)N * 64 * 2);
    float* alsrc1 = (float*)alloc((size_t)N * 4 * 4);
    float* aldst1 = (float*)alloc((size_t)N * 4 * 4);
    float* alsrc2 = (float*)alloc((size_t)N * 4 * 4);
    float* aldst2 = (float*)alloc((size_t)N * 4 * 4);
    int* cnt = (int*)alloc((size_t)N * 4);
    int* rp  = (int*)alloc((size_t)N * 4);
    int* cur = (int*)alloc((size_t)N * 4);
    int* q   = (int*)alloc(64);
    int* bs  = (int*)alloc(1024 * 4);
    int* col = (int*)alloc((size_t)E * 4);

    unsigned pdiv = (unsigned)((N + 7) / 8);
    unsigned M = (unsigned)(((1ull << 35) + pdiv - 1) / pdiv);
    int nchunks = (E + SCS - 1) / SCS;

    int nb = (N + 255) / 256;
    hipMemsetAsync(cnt, 0, (size_t)N * 4, stream);
    hipMemsetAsync(cur, 0, (size_t)N * 4, stream);
    hipMemsetAsync(q, 0, 64, stream);
    hist_k<<<(E + 255) / 256, 256, 0, stream>>>(ei, cnt, E);
    scan1_k<<<nb, 256, 0, stream>>>(cnt, rp, bs, N);
    scan2_k<<<1, 1024, 0, stream>>>(bs, nb);
    scan3_k<<<nb, 256, 0, stream>>>(rp, bs, N);
    scatter_pin_k<<<1024, 256, 0, stream>>>(ei, rp, cur, col, q, E, nchunks, M);
    scatter_fix_k<<<64, 256, 0, stream>>>(ei, rp, cur, col, q, E, nchunks, M);

    gemm1_k<<<768, 256, 0, stream>>>(x, W1, as1, ad1, h1h, alsrc1, aldst1, N);
    node1_k<<<(N + 3) / 4, 256, 0, stream>>>(h1h, alsrc1, aldst1, rp, cnt, col, b1, h1o, N);
    gemm2_k<<<768, 256, 0, stream>>>(h1o, W2, as2, ad2, h2h, alsrc2, aldst2, N);
    node2_k<<<(N + 3) / 4, 256, 0, stream>>>(h2h, alsrc2, aldst2, rp, cnt, col, b2, out, N);
}

// Round 5
// 499.136 us; speedup vs baseline: 1.6382x; 1.0407x over previous
//
#include <hip/hip_runtime.h>
#include <hip/hip_fp16.h>
#include <cstdint>
#include <cstddef>

#define NEG 0.2f
#define SCS 4096   // scatter chunk size (edges)

// ---------------- CSR build ----------------

__global__ __launch_bounds__(256) void hist_k(const int* __restrict__ ei, int* __restrict__ cnt, int E) {
    int i = blockIdx.x * 256 + threadIdx.x;
    if (i < E) atomicAdd(&cnt[__builtin_nontemporal_load(ei + E + i)], 1);
}

__global__ __launch_bounds__(256) void scan1_k(const int* __restrict__ cnt, int* __restrict__ rp,
                                               int* __restrict__ bs, int N) {
    __shared__ int sm[256];
    int t = threadIdx.x, i = blockIdx.x * 256 + t;
    int v = (i < N) ? cnt[i] : 0;
    sm[t] = v; __syncthreads();
    for (int off = 1; off < 256; off <<= 1) {
        int u = (t >= off) ? sm[t - off] : 0;
        __syncthreads();
        sm[t] += u;
        __syncthreads();
    }
    if (i < N) rp[i] = sm[t] - v;          // exclusive within block
    if (t == 255) bs[blockIdx.x] = sm[255];
}

__global__ __launch_bounds__(1024) void scan2_k(int* __restrict__ bs, int nb) {
    __shared__ int sm[1024];
    int t = threadIdx.x;
    int v = (t < nb) ? bs[t] : 0;
    sm[t] = v; __syncthreads();
    for (int off = 1; off < 1024; off <<= 1) {
        int u = (t >= off) ? sm[t - off] : 0;
        __syncthreads();
        sm[t] += u;
        __syncthreads();
    }
    if (t < nb) bs[t] = sm[t] - v;         // exclusive block offsets
}

__global__ __launch_bounds__(256) void scan3_k(int* __restrict__ rp, const int* __restrict__ bs, int N) {
    int i = blockIdx.x * 256 + threadIdx.x;
    if (i < N) rp[i] += bs[blockIdx.x];
}

// XCD-pinned scatter. Non-temporal ei loads keep the streaming scan out of L2 so
// the partially-filled col/cur lines of this XCD's partition stay resident until
// the line completes -> one eviction per line instead of ~16.
__global__ __launch_bounds__(256) void scatter_pin_k(const int* __restrict__ ei, const int* __restrict__ rp,
                                                     int* __restrict__ cur, int* __restrict__ col,
                                                     int* __restrict__ q, int E, int nchunks, unsigned M) {
    __shared__ int smc;
    int xcd = __builtin_amdgcn_s_getreg(6164) & 7;   // hwreg(HW_REG_XCC_ID=20, off 0, sz 4)
    for (;;) {
        if (threadIdx.x == 0) smc = atomicAdd(&q[xcd], 1);
        __syncthreads();
        int c = smc;
        __syncthreads();
        if (c >= nchunks) return;
        int hi = min(c * SCS + SCS, E);
        for (int i = c * SCS + threadIdx.x; i < hi; i += 256) {
            int d = __builtin_nontemporal_load(ei + E + i);
            int part = (int)(((unsigned long long)(unsigned)d * M) >> 35);
            if (part == xcd) {
                int s = __builtin_nontemporal_load(ei + i);
                int pos = rp[d] + atomicAdd(&cur[d], 1);
                col[pos] = s;
            }
        }
    }
}

// Safety net: drains chunks scatter_pin_k left unclaimed (no-op in practice).
__global__ __launch_bounds__(256) void scatter_fix_k(const int* __restrict__ ei, const int* __restrict__ rp,
                                                     int* __restrict__ cur, int* __restrict__ col,
                                                     int* __restrict__ q, int E, int nchunks, unsigned M) {
    __shared__ int smc;
    for (int p = 0; p < 8; p++) {
        for (;;) {
            if (threadIdx.x == 0) smc = atomicAdd(&q[p], 1);
            __syncthreads();
            int c = smc;
            __syncthreads();
            if (c >= nchunks) break;
            int hi = min(c * SCS + SCS, E);
            for (int i = c * SCS + threadIdx.x; i < hi; i += 256) {
                int d = __builtin_nontemporal_load(ei + E + i);
                int part = (int)(((unsigned long long)(unsigned)d * M) >> 35);
                if (part == p) {
                    int s = __builtin_nontemporal_load(ei + i);
                    int pos = rp[d] + atomicAdd(&cur[d], 1);
                    col[pos] = s;
                }
            }
        }
    }
}

// ---------------- Layer 1 GEMM: h1 = x @ W1 (fp16 out), register-tiled ----------------

__global__ __launch_bounds__(256) void gemm1_k(const float* __restrict__ x, const float* __restrict__ W,
                                               const float* __restrict__ a_src, const float* __restrict__ a_dst,
                                               __half* __restrict__ h, float* __restrict__ alsrc,
                                               float* __restrict__ aldst, int N) {
    __shared__ float Bs[128 * 64];
    __shared__ float xs[64][68];
    int t = threadIdx.x;
    for (int i = t; i < 128 * 64 / 4; i += 256)
        ((float4*)Bs)[i] = ((const float4*)W)[i];
    int ct = t & 15, rt = t >> 4;
    int head = ct >> 2, cq = ct & 3;
    float asv[4], adv[4];
    #pragma unroll
    for (int j = 0; j < 4; j++) {
        asv[j] = a_src[head * 16 + 4 * cq + j];
        adv[j] = a_dst[head * 16 + 4 * cq + j];
    }
    int ntiles = (N + 63) >> 6;
    for (int tile = blockIdx.x; tile < ntiles; tile += gridDim.x) {
        int r0 = tile << 6;
        float acc[4][4];
        #pragma unroll
        for (int i = 0; i < 4; i++)
            #pragma unroll
            for (int j = 0; j < 4; j++) acc[i][j] = 0.f;
        for (int kc = 0; kc < 128; kc += 64) {
            __syncthreads();
            int srow = t >> 4, sf4 = t & 15;
            #pragma unroll
            for (int p = 0; p < 4; p++) {
                int r = r0 + srow + 16 * p;
                float4 v = make_float4(0.f, 0.f, 0.f, 0.f);
                if (r < N) v = *(const float4*)(x + (size_t)r * 128 + kc + 4 * sf4);
                *(float4*)&xs[srow + 16 * p][4 * sf4] = v;
            }
            __syncthreads();
            #pragma unroll 4
            for (int k = 0; k < 64; k++) {
                float4 bv = *(float4*)&Bs[(kc + k) * 64 + 4 * ct];
                #pragma unroll
                for (int i = 0; i < 4; i++) {
                    float xv = xs[4 * rt + i][k];
                    acc[i][0] = fmaf(xv, bv.x, acc[i][0]);
                    acc[i][1] = fmaf(xv, bv.y, acc[i][1]);
                    acc[i][2] = fmaf(xv, bv.z, acc[i][2]);
                    acc[i][3] = fmaf(xv, bv.w, acc[i][3]);
                }
            }
        }
        #pragma unroll
        for (int i = 0; i < 4; i++) {
            int r = r0 + 4 * rt + i;
            float ps = 0.f, pd = 0.f;
            #pragma unroll
            for (int j = 0; j < 4; j++) {
                ps = fmaf(acc[i][j], asv[j], ps);
                pd = fmaf(acc[i][j], adv[j], pd);
            }
            ps += __shfl_xor(ps, 1); ps += __shfl_xor(ps, 2);
            pd += __shfl_xor(pd, 1); pd += __shfl_xor(pd, 2);
            if (r < N) {
                __half2 h0 = __floats2half2_rn(acc[i][0], acc[i][1]);
                __half2 h1 = __floats2half2_rn(acc[i][2], acc[i][3]);
                *(__half2*)(h + (size_t)r * 64 + 4 * ct) = h0;
                *(__half2*)(h + (size_t)r * 64 + 4 * ct + 2) = h1;
                if (cq == 0) { alsrc[r * 4 + head] = ps; aldst[r * 4 + head] = pd; }
            }
        }
    }
}

// ---------------- Layer 1 node aggregation (fp16 packed, 2-edge pipelined) ----------------

__global__ __launch_bounds__(256) void node1_k(const __half* __restrict__ h, const float* __restrict__ alsrc,
                                               const float* __restrict__ aldst, const int* __restrict__ rp,
                                               const int* __restrict__ cnt, const int* __restrict__ col,
                                               const float* __restrict__ bias, __half* __restrict__ out, int N) {
    int wid = (blockIdx.x * 256 + threadIdx.x) >> 6;
    int lane = threadIdx.x & 63;
    if (wid >= N) return;
    int d = wid;
    int g = lane >> 4;
    int c = lane & 15;
    int head = c >> 2;
    float ad = aldst[d * 4 + head];
    float den = 0.f;
    __half2 acc0 = __float2half2_rn(0.f), acc1 = __float2half2_rn(0.f);
    const __half2* hb = (const __half2*)h;
    unsigned co = 2u * c;
    if (g == 0) {  // self loop
        float e0 = alsrc[d * 4 + head] + ad;
        float w = __expf(e0 > 0.f ? e0 : NEG * e0);
        den = w;
        __half2 w2 = __float2half2_rn(w);
        uint2 u = *(const uint2*)(hb + ((unsigned)d << 5) + co);
        acc0 = __hfma2(w2, *(__half2*)&u.x, acc0);
        acc1 = __hfma2(w2, *(__half2*)&u.y, acc1);
    }
    int start = rp[d], deg = cnt[d];
    int i = g;
    for (; i + 4 < deg; i += 8) {
        int s0 = col[start + i];
        int s1 = col[start + i + 4];
        uint2 u0 = *(const uint2*)(hb + ((unsigned)s0 << 5) + co);
        uint2 u1 = *(const uint2*)(hb + ((unsigned)s1 << 5) + co);
        float e0 = alsrc[s0 * 4 + head] + ad;
        float e1 = alsrc[s1 * 4 + head] + ad;
        float w0 = __expf(e0 > 0.f ? e0 : NEG * e0);
        float w1 = __expf(e1 > 0.f ? e1 : NEG * e1);
        den += w0 + w1;
        __half2 w20 = __float2half2_rn(w0), w21 = __float2half2_rn(w1);
        acc0 = __hfma2(w20, *(__half2*)&u0.x, acc0);
        acc1 = __hfma2(w20, *(__half2*)&u0.y, acc1);
        acc0 = __hfma2(w21, *(__half2*)&u1.x, acc0);
        acc1 = __hfma2(w21, *(__half2*)&u1.y, acc1);
    }
    if (i < deg) {
        int s = col[start + i];
        uint2 u = *(const uint2*)(hb + ((unsigned)s << 5) + co);
        float e = alsrc[s * 4 + head] + ad;
        float w = __expf(e > 0.f ? e : NEG * e);
        den += w;
        __half2 w2 = __float2half2_rn(w);
        acc0 = __hfma2(w2, *(__half2*)&u.x, acc0);
        acc1 = __hfma2(w2, *(__half2*)&u.y, acc1);
    }
    float2 f0 = __half22float2(acc0), f1 = __half22float2(acc1);
    float a0 = f0.x, a1 = f0.y, a2 = f1.x, a3 = f1.y;
    #pragma unroll
    for (int off = 16; off <= 32; off <<= 1) {
        a0 += __shfl_xor(a0, off); a1 += __shfl_xor(a1, off);
        a2 += __shfl_xor(a2, off); a3 += __shfl_xor(a3, off);
        den += __shfl_xor(den, off);
    }
    if (lane < 16) {
        float inv = 1.f / den;
        float4 b = *(const float4*)(bias + 4 * c);
        __half2 o0 = __floats2half2_rn(a0 * inv + b.x, a1 * inv + b.y);
        __half2 o1 = __floats2half2_rn(a2 * inv + b.z, a3 * inv + b.w);
        uint2 o; o.x = *(unsigned*)&o0; o.y = *(unsigned*)&o1;
        *(uint2*)(out + (size_t)d * 64 + 4 * c) = o;
    }
}

// ---------------- Layer 2 GEMM: h2 = h1o(fp16) @ W2 (fp16 out), register-tiled ----------------

__global__ __launch_bounds__(256) void gemm2_k(const __half* __restrict__ xh, const float* __restrict__ W,
                                               const float* __restrict__ a_src, const float* __restrict__ a_dst,
                                               __half* __restrict__ h, float* __restrict__ alsrc,
                                               float* __restrict__ aldst, int N) {
    __shared__ float Bs[64 * 128];
    __shared__ float xs[64][68];
    int t = threadIdx.x;
    for (int i = t; i < 64 * 128 / 4; i += 256)
        ((float4*)Bs)[i] = ((const float4*)W)[i];
    int ct = t & 15, rt = t >> 4;
    int hA = ct >> 3, cq = ct & 7;
    float asA[4], adA[4], asB[4], adB[4];
    #pragma unroll
    for (int j = 0; j < 4; j++) {
        asA[j] = a_src[hA * 32 + 4 * cq + j];
        adA[j] = a_dst[hA * 32 + 4 * cq + j];
        asB[j] = a_src[(2 + hA) * 32 + 4 * cq + j];
        adB[j] = a_dst[(2 + hA) * 32 + 4 * cq + j];
    }
    int ntiles = (N + 63) >> 6;
    for (int tile = blockIdx.x; tile < ntiles; tile += gridDim.x) {
        int r0 = tile << 6;
        float accA[4][4], accB[4][4];
        #pragma unroll
        for (int i = 0; i < 4; i++)
            #pragma unroll
            for (int j = 0; j < 4; j++) { accA[i][j] = 0.f; accB[i][j] = 0.f; }
        __syncthreads();
        int srow = t >> 3, su = t & 7;
        #pragma unroll
        for (int p = 0; p < 2; p++) {
            int r = r0 + srow + 32 * p;
            float2 g0 = make_float2(0.f, 0.f), g1 = g0, g2 = g0, g3 = g0;
            if (r < N) {
                uint4 u = *(const uint4*)(xh + (size_t)r * 64 + 8 * su);
                const __half2* hp = (const __half2*)&u;
                g0 = __half22float2(hp[0]); g1 = __half22float2(hp[1]);
                g2 = __half22float2(hp[2]); g3 = __half22float2(hp[3]);
            }
            *(float4*)&xs[srow + 32 * p][8 * su] = make_float4(g0.x, g0.y, g1.x, g1.y);
            *(float4*)&xs[srow + 32 * p][8 * su + 4] = make_float4(g2.x, g2.y, g3.x, g3.y);
        }
        __syncthreads();
        #pragma unroll 4
        for (int k = 0; k < 64; k++) {
            float4 bA = *(float4*)&Bs[k * 128 + 4 * ct];
            float4 bB = *(float4*)&Bs[k * 128 + 64 + 4 * ct];
            #pragma unroll
            for (int i = 0; i < 4; i++) {
                float xv = xs[4 * rt + i][k];
                accA[i][0] = fmaf(xv, bA.x, accA[i][0]);
                accA[i][1] = fmaf(xv, bA.y, accA[i][1]);
                accA[i][2] = fmaf(xv, bA.z, accA[i][2]);
                accA[i][3] = fmaf(xv, bA.w, accA[i][3]);
                accB[i][0] = fmaf(xv, bB.x, accB[i][0]);
                accB[i][1] = fmaf(xv, bB.y, accB[i][1]);
                accB[i][2] = fmaf(xv, bB.z, accB[i][2]);
                accB[i][3] = fmaf(xv, bB.w, accB[i][3]);
            }
        }
        #pragma unroll
        for (int i = 0; i < 4; i++) {
            int r = r0 + 4 * rt + i;
            float psA = 0.f, pdA = 0.f, psB = 0.f, pdB = 0.f;
            #pragma unroll
            for (int j = 0; j < 4; j++) {
                psA = fmaf(accA[i][j], asA[j], psA);
                pdA = fmaf(accA[i][j], adA[j], pdA);
                psB = fmaf(accB[i][j], asB[j], psB);
                pdB = fmaf(accB[i][j], adB[j], pdB);
            }
            #pragma unroll
            for (int off = 1; off <= 4; off <<= 1) {
                psA += __shfl_xor(psA, off); pdA += __shfl_xor(pdA, off);
                psB += __shfl_xor(psB, off); pdB += __shfl_xor(pdB, off);
            }
            if (r < N) {
                __half2 hA0 = __floats2half2_rn(accA[i][0], accA[i][1]);
                __half2 hA1 = __floats2half2_rn(accA[i][2], accA[i][3]);
                __half2 hB0 = __floats2half2_rn(accB[i][0], accB[i][1]);
                __half2 hB1 = __floats2half2_rn(accB[i][2], accB[i][3]);
                *(__half2*)(h + (size_t)r * 128 + 4 * ct) = hA0;
                *(__half2*)(h + (size_t)r * 128 + 4 * ct + 2) = hA1;
                *(__half2*)(h + (size_t)r * 128 + 64 + 4 * ct) = hB0;
                *(__half2*)(h + (size_t)r * 128 + 64 + 4 * ct + 2) = hB1;
                if (cq == 0) {
                    alsrc[r * 4 + hA] = psA;     alsrc[r * 4 + 2 + hA] = psB;
                    aldst[r * 4 + hA] = pdA;     aldst[r * 4 + 2 + hA] = pdB;
                }
            }
        }
    }
}

// ---------------- Layer 2 node aggregation (2-edge pipelined) + epilogue ----------------

__global__ __launch_bounds__(256) void node2_k(const __half* __restrict__ h, const float* __restrict__ alsrc,
                                               const float* __restrict__ aldst, const int* __restrict__ rp,
                                               const int* __restrict__ cnt, const int* __restrict__ col,
                                               const float* __restrict__ bias, float* __restrict__ out, int N) {
    int wid = (blockIdx.x * 256 + threadIdx.x) >> 6;
    int lane = threadIdx.x & 63;
    if (wid >= N) return;
    int d = wid;
    int g = lane >> 4;
    int c = lane & 15;
    int head = c >> 2;
    float ad = aldst[d * 4 + head];
    float den = 0.f;
    __half2 acc[4];
    #pragma unroll
    for (int j = 0; j < 4; j++) acc[j] = __float2half2_rn(0.f);
    const __half2* hb = (const __half2*)h;
    unsigned co = 4u * c;
    if (g == 0) {  // self loop
        float e0 = alsrc[d * 4 + head] + ad;
        float w = __expf(e0 > 0.f ? e0 : NEG * e0);
        den = w;
        __half2 w2 = __float2half2_rn(w);
        uint4 u = *(const uint4*)(hb + ((unsigned)d << 6) + co);
        const __half2* hp = (const __half2*)&u;
        #pragma unroll
        for (int j = 0; j < 4; j++) acc[j] = __hfma2(w2, hp[j], acc[j]);
    }
    int start = rp[d], deg = cnt[d];
    int i = g;
    for (; i + 4 < deg; i += 8) {
        int s0 = col[start + i];
        int s1 = col[start + i + 4];
        uint4 u0 = *(const uint4*)(hb + ((unsigned)s0 << 6) + co);
        uint4 u1 = *(const uint4*)(hb + ((unsigned)s1 << 6) + co);
        float e0 = alsrc[s0 * 4 + head] + ad;
        float e1 = alsrc[s1 * 4 + head] + ad;
        float w0 = __expf(e0 > 0.f ? e0 : NEG * e0);
        float w1 = __expf(e1 > 0.f ? e1 : NEG * e1);
        den += w0 + w1;
        __half2 w20 = __float2half2_rn(w0), w21 = __float2half2_rn(w1);
        const __half2* hp0 = (const __half2*)&u0;
        const __half2* hp1 = (const __half2*)&u1;
        #pragma unroll
        for (int j = 0; j < 4; j++) acc[j] = __hfma2(w20, hp0[j], acc[j]);
        #pragma unroll
        for (int j = 0; j < 4; j++) acc[j] = __hfma2(w21, hp1[j], acc[j]);
    }
    if (i < deg) {
        int s = col[start + i];
        uint4 u = *(const uint4*)(hb + ((unsigned)s << 6) + co);
        float e = alsrc[s * 4 + head] + ad;
        float w = __expf(e > 0.f ? e : NEG * e);
        den += w;
        __half2 w2 = __float2half2_rn(w);
        const __half2* hp = (const __half2*)&u;
        #pragma unroll
        for (int j = 0; j < 4; j++) acc[j] = __hfma2(w2, hp[j], acc[j]);
    }
    float a[8];
    #pragma unroll
    for (int j = 0; j < 4; j++) {
        float2 f = __half22float2(acc[j]);
        a[2 * j] = f.x; a[2 * j + 1] = f.y;
    }
    #pragma unroll
    for (int off = 16; off <= 32; off <<= 1) {
        #pragma unroll
        for (int j = 0; j < 8; j++) a[j] += __shfl_xor(a[j], off);
        den += __shfl_xor(den, off);
    }
    float inv = 1.f / den;
    float v[8];
    #pragma unroll
    for (int j = 0; j < 8; j++) v[j] = a[j] * inv;
    #pragma unroll
    for (int off = 4; off <= 8; off <<= 1) {
        #pragma unroll
        for (int j = 0; j < 8; j++) v[j] += __shfl_xor(v[j], off);
    }
    int jc = c & 3;
    float ev[8];
    #pragma unroll
    for (int j = 0; j < 8; j++) {
        float val = 0.25f * v[j] + bias[8 * jc + j];
        ev[j] = val > 0.f ? val : expm1f(val);
    }
    float mx = ev[0];
    #pragma unroll
    for (int j = 1; j < 8; j++) mx = fmaxf(mx, ev[j]);
    #pragma unroll
    for (int off = 1; off <= 2; off <<= 1) mx = fmaxf(mx, __shfl_xor(mx, off));
    float sum = 0.f;
    #pragma unroll
    for (int j = 0; j < 8; j++) sum += __expf(ev[j] - mx);
    #pragma unroll
    for (int off = 1; off <= 2; off <<= 1) sum += __shfl_xor(sum, off);
    float ls = mx + __logf(sum);
    if (lane < 4) {
        float4 o0, o1;
        o0.x = ev[0] - ls; o0.y = ev[1] - ls; o0.z = ev[2] - ls; o0.w = ev[3] - ls;
        o1.x = ev[4] - ls; o1.y = ev[5] - ls; o1.z = ev[6] - ls; o1.w = ev[7] - ls;
        *(float4*)(out + (size_t)d * 32 + 8 * jc) = o0;
        *(float4*)(out + (size_t)d * 32 + 8 * jc + 4) = o1;
    }
}

// ---------------- launch ----------------

extern "C" void kernel_launch(void* const* d_in, const int* in_sizes, int n_in,
                              void* d_out, int out_size, void* d_ws, size_t ws_size,
                              hipStream_t stream) {
    const float* x   = (const float*)d_in[0];
    const int*   ei  = (const int*)d_in[1];
    const float* W1  = (const float*)d_in[2];
    const float* as1 = (const float*)d_in[3];
    const float* ad1 = (const float*)d_in[4];
    const float* b1  = (const float*)d_in[5];
    const float* W2  = (const float*)d_in[6];
    const float* as2 = (const float*)d_in[7];
    const float* ad2 = (const float*)d_in[8];
    const float* b2  = (const float*)d_in[9];
    float* out = (float*)d_out;
    int N = in_sizes[0] / 128;
    int E = in_sizes[1] / 2;

    char* base = (char*)d_ws;
    size_t off = 0;
    auto alloc = [&](size_t bytes) -> char* {
        char* p = base + off;
        off = (off + bytes + 255) & ~(size_t)255;
        return p;
    };
    __half* h1h   = (__half*)alloc((size_t)N * 64 * 2);
    __half* h2h   = (__half*)alloc((size_t)N * 128 * 2);
    __half* h1o   = (__half*)alloc((size_t)N * 64 * 2);
    float* alsrc1 = (float*)alloc((size_t)N * 4 * 4);
    float* aldst1 = (float*)alloc((size_t)N * 4 * 4);
    float* alsrc2 = (float*)alloc((size_t)N * 4 * 4);
    float* aldst2 = (float*)alloc((size_t)N * 4 * 4);
    int* cnt = (int*)alloc((size_t)N * 4);
    int* rp  = (int*)alloc((size_t)N * 4);
    int* cur = (int*)alloc((size_t)N * 4);
    int* q   = (int*)alloc(64);
    int* bs  = (int*)alloc(1024 * 4);
    int* col = (int*)alloc((size_t)E * 4);

    unsigned pdiv = (unsigned)((N + 7) / 8);
    unsigned M = (unsigned)(((1ull << 35) + pdiv - 1) / pdiv);
    int nchunks = (E + SCS - 1) / SCS;

    int nb = (N + 255) / 256;
    hipMemsetAsync(cnt, 0, (size_t)N * 4, stream);
    hipMemsetAsync(cur, 0, (size_t)N * 4, stream);
    hipMemsetAsync(q, 0, 64, stream);
    hist_k<<<(E + 255) / 256, 256, 0, stream>>>(ei, cnt, E);
    scan1_k<<<nb, 256, 0, stream>>>(cnt, rp, bs, N);
    scan2_k<<<1, 1024, 0, stream>>>(bs, nb);
    scan3_k<<<nb, 256, 0, stream>>>(rp, bs, N);
    scatter_pin_k<<<1024, 256, 0, stream>>>(ei, rp, cur, col, q, E, nchunks, M);
    scatter_fix_k<<<64, 256, 0, stream>>>(ei, rp, cur, col, q, E, nchunks, M);

    gemm1_k<<<768, 256, 0, stream>>>(x, W1, as1, ad1, h1h, alsrc1, aldst1, N);
    node1_k<<<(N + 3) / 4, 256, 0, stream>>>(h1h, alsrc1, aldst1, rp, cnt, col, b1, h1o, N);
    gemm2_k<<<768, 256, 0, stream>>>(h1o, W2, as2, ad2, h2h, alsrc2, aldst2, N);
    node2_k<<<(N + 3) / 4, 256, 0, stream>>>(h2h, alsrc2, aldst2, rp, cnt, col, b2, out, N);
}

// Round 6
// 423.570 us; speedup vs baseline: 1.9304x; 1.1784x over previous
//
#include <hip/hip_runtime.h>
#include <hip/hip_fp16.h>
#include <cstdint>
#include <cstddef>

#define NEG 0.2f
#define TILE 4096   // edges per partition tile

// ---------------- CSR build: hist + scan ----------------

__global__ __launch_bounds__(256) void hist_k(const int* __restrict__ ei, int* __restrict__ cnt, int E) {
    int i = blockIdx.x * 256 + threadIdx.x;
    if (i < E) atomicAdd(&cnt[__builtin_nontemporal_load(ei + E + i)], 1);
}

__global__ __launch_bounds__(256) void scan1_k(const int* __restrict__ cnt, int* __restrict__ rp,
                                               int* __restrict__ bs, int N) {
    __shared__ int sm[256];
    int t = threadIdx.x, i = blockIdx.x * 256 + t;
    int v = (i < N) ? cnt[i] : 0;
    sm[t] = v; __syncthreads();
    for (int off = 1; off < 256; off <<= 1) {
        int u = (t >= off) ? sm[t - off] : 0;
        __syncthreads();
        sm[t] += u;
        __syncthreads();
    }
    if (i < N) rp[i] = sm[t] - v;          // exclusive within block
    if (t == 255) bs[blockIdx.x] = sm[255];
}

__global__ __launch_bounds__(1024) void scan2_k(int* __restrict__ bs, int nb) {
    __shared__ int sm[1024];
    int t = threadIdx.x;
    int v = (t < nb) ? bs[t] : 0;
    sm[t] = v; __syncthreads();
    for (int off = 1; off < 1024; off <<= 1) {
        int u = (t >= off) ? sm[t - off] : 0;
        __syncthreads();
        sm[t] += u;
        __syncthreads();
    }
    if (t < nb) bs[t] = sm[t] - v;         // exclusive block offsets
}

__global__ __launch_bounds__(256) void scan3_k(int* __restrict__ rp, const int* __restrict__ bs, int N) {
    int i = blockIdx.x * 256 + threadIdx.x;
    if (i < N) rp[i] += bs[blockIdx.x];
}

// Seed per-bucket global cursors with the bucket's CSR region start.
__global__ __launch_bounds__(256) void initA_k(const int* __restrict__ rp, int* __restrict__ curA, int nbk) {
    int b = threadIdx.x;
    if (b < nbk) curA[b] = rp[b << 9];
}

// ---------------- Phase A: LDS-staged partition of edges into 512-node buckets ----------------
// Per 4096-edge tile: LDS count -> LDS scan -> local counting-sort -> reserve global
// segment per bucket (atomicAdd on curA) -> coalesced segment writes of (src,dst) pairs.

__global__ __launch_bounds__(256) void partA_k(const int* __restrict__ ei, int* __restrict__ curA,
                                               uint2* __restrict__ pairs, int E, int nbk) {
    __shared__ int scnt[256];
    __shared__ int sc[256];
    __shared__ int sbase[256];
    __shared__ int gbase[256];
    __shared__ int cur2[256];
    __shared__ int ssrc[TILE];
    __shared__ int sdst[TILE];
    int t = threadIdx.x;
    int ntiles = (E + TILE - 1) / TILE;
    for (int tile = blockIdx.x; tile < ntiles; tile += gridDim.x) {
        int base = tile * TILE;
        int cntE = min(TILE, E - base);
        scnt[t] = 0;
        __syncthreads();
        int mys[16], myd[16];
        #pragma unroll
        for (int j = 0; j < 16; j++) {
            int i = base + t + 256 * j;
            int s = 0, d = -1;
            if (i < E) {
                s = __builtin_nontemporal_load(ei + i);
                d = __builtin_nontemporal_load(ei + E + i);
            }
            mys[j] = s; myd[j] = d;
            if (d >= 0) atomicAdd(&scnt[d >> 9], 1);
        }
        __syncthreads();
        // inclusive scan of scnt -> sc
        sc[t] = scnt[t];
        __syncthreads();
        for (int off = 1; off < 256; off <<= 1) {
            int u = (t >= off) ? sc[t - off] : 0;
            __syncthreads();
            sc[t] += u;
            __syncthreads();
        }
        int myb = sc[t] - scnt[t];
        sbase[t] = myb;
        cur2[t] = myb;
        if (t < nbk && scnt[t] > 0) gbase[t] = atomicAdd(&curA[t], scnt[t]);
        __syncthreads();
        // local counting-sort placement into LDS
        #pragma unroll
        for (int j = 0; j < 16; j++) {
            int d = myd[j];
            if (d >= 0) {
                int b = d >> 9;
                int pos = atomicAdd(&cur2[b], 1);
                ssrc[pos] = mys[j];
                sdst[pos] = d;
            }
        }
        __syncthreads();
        // coalesced segment write-out
        for (int i = t; i < cntE; i += 256) {
            int d = sdst[i];
            int b = d >> 9;
            int addr = gbase[b] + (i - sbase[b]);
            pairs[addr] = make_uint2((unsigned)ssrc[i], (unsigned)d);
        }
        __syncthreads();
    }
}

// ---------------- Phase B: per-bucket scatter with LDS cursors ----------------
// One workgroup per bucket; col writes confined to a ~33 KB single-writer window.

__global__ __launch_bounds__(256) void partB_k(const uint2* __restrict__ pairs, const int* __restrict__ rp,
                                               int* __restrict__ col, int E, int N) {
    __shared__ int cur[512];
    int b = blockIdx.x;
    int t = threadIdx.x;
    int d0 = b << 9;
    cur[t] = 0; cur[t + 256] = 0;
    __syncthreads();
    int hi = d0 + 512;
    int ebase = rp[d0];
    int eend = (hi >= N) ? E : rp[hi];
    for (int j = ebase + t; j < eend; j += 256) {
        uint2 p = pairs[j];
        int d = (int)p.y;
        int pos = rp[d] + atomicAdd(&cur[d - d0], 1);
        col[pos] = (int)p.x;
    }
}

// ---------------- Layer 1 GEMM: h1 = x @ W1 (fp16 out), register-tiled ----------------

__global__ __launch_bounds__(256) void gemm1_k(const float* __restrict__ x, const float* __restrict__ W,
                                               const float* __restrict__ a_src, const float* __restrict__ a_dst,
                                               __half* __restrict__ h, float* __restrict__ alsrc,
                                               float* __restrict__ aldst, int N) {
    __shared__ float Bs[128 * 64];
    __shared__ float xs[64][68];
    int t = threadIdx.x;
    for (int i = t; i < 128 * 64 / 4; i += 256)
        ((float4*)Bs)[i] = ((const float4*)W)[i];
    int ct = t & 15, rt = t >> 4;
    int head = ct >> 2, cq = ct & 3;
    float asv[4], adv[4];
    #pragma unroll
    for (int j = 0; j < 4; j++) {
        asv[j] = a_src[head * 16 + 4 * cq + j];
        adv[j] = a_dst[head * 16 + 4 * cq + j];
    }
    int ntiles = (N + 63) >> 6;
    for (int tile = blockIdx.x; tile < ntiles; tile += gridDim.x) {
        int r0 = tile << 6;
        float acc[4][4];
        #pragma unroll
        for (int i = 0; i < 4; i++)
            #pragma unroll
            for (int j = 0; j < 4; j++) acc[i][j] = 0.f;
        for (int kc = 0; kc < 128; kc += 64) {
            __syncthreads();
            int srow = t >> 4, sf4 = t & 15;
            #pragma unroll
            for (int p = 0; p < 4; p++) {
                int r = r0 + srow + 16 * p;
                float4 v = make_float4(0.f, 0.f, 0.f, 0.f);
                if (r < N) v = *(const float4*)(x + (size_t)r * 128 + kc + 4 * sf4);
                *(float4*)&xs[srow + 16 * p][4 * sf4] = v;
            }
            __syncthreads();
            #pragma unroll 4
            for (int k = 0; k < 64; k++) {
                float4 bv = *(float4*)&Bs[(kc + k) * 64 + 4 * ct];
                #pragma unroll
                for (int i = 0; i < 4; i++) {
                    float xv = xs[4 * rt + i][k];
                    acc[i][0] = fmaf(xv, bv.x, acc[i][0]);
                    acc[i][1] = fmaf(xv, bv.y, acc[i][1]);
                    acc[i][2] = fmaf(xv, bv.z, acc[i][2]);
                    acc[i][3] = fmaf(xv, bv.w, acc[i][3]);
                }
            }
        }
        #pragma unroll
        for (int i = 0; i < 4; i++) {
            int r = r0 + 4 * rt + i;
            float ps = 0.f, pd = 0.f;
            #pragma unroll
            for (int j = 0; j < 4; j++) {
                ps = fmaf(acc[i][j], asv[j], ps);
                pd = fmaf(acc[i][j], adv[j], pd);
            }
            ps += __shfl_xor(ps, 1); ps += __shfl_xor(ps, 2);
            pd += __shfl_xor(pd, 1); pd += __shfl_xor(pd, 2);
            if (r < N) {
                __half2 h0 = __floats2half2_rn(acc[i][0], acc[i][1]);
                __half2 h1 = __floats2half2_rn(acc[i][2], acc[i][3]);
                *(__half2*)(h + (size_t)r * 64 + 4 * ct) = h0;
                *(__half2*)(h + (size_t)r * 64 + 4 * ct + 2) = h1;
                if (cq == 0) { alsrc[r * 4 + head] = ps; aldst[r * 4 + head] = pd; }
            }
        }
    }
}

// ---------------- Layer 1 node aggregation (fp16 packed, 2-edge pipelined) ----------------

__global__ __launch_bounds__(256) void node1_k(const __half* __restrict__ h, const float* __restrict__ alsrc,
                                               const float* __restrict__ aldst, const int* __restrict__ rp,
                                               const int* __restrict__ cnt, const int* __restrict__ col,
                                               const float* __restrict__ bias, __half* __restrict__ out, int N) {
    int wid = (blockIdx.x * 256 + threadIdx.x) >> 6;
    int lane = threadIdx.x & 63;
    if (wid >= N) return;
    int d = wid;
    int g = lane >> 4;
    int c = lane & 15;
    int head = c >> 2;
    float ad = aldst[d * 4 + head];
    float den = 0.f;
    __half2 acc0 = __float2half2_rn(0.f), acc1 = __float2half2_rn(0.f);
    const __half2* hb = (const __half2*)h;
    unsigned co = 2u * c;
    if (g == 0) {  // self loop
        float e0 = alsrc[d * 4 + head] + ad;
        float w = __expf(e0 > 0.f ? e0 : NEG * e0);
        den = w;
        __half2 w2 = __float2half2_rn(w);
        uint2 u = *(const uint2*)(hb + ((unsigned)d << 5) + co);
        acc0 = __hfma2(w2, *(__half2*)&u.x, acc0);
        acc1 = __hfma2(w2, *(__half2*)&u.y, acc1);
    }
    int start = rp[d], deg = cnt[d];
    int i = g;
    for (; i + 4 < deg; i += 8) {
        int s0 = col[start + i];
        int s1 = col[start + i + 4];
        uint2 u0 = *(const uint2*)(hb + ((unsigned)s0 << 5) + co);
        uint2 u1 = *(const uint2*)(hb + ((unsigned)s1 << 5) + co);
        float e0 = alsrc[s0 * 4 + head] + ad;
        float e1 = alsrc[s1 * 4 + head] + ad;
        float w0 = __expf(e0 > 0.f ? e0 : NEG * e0);
        float w1 = __expf(e1 > 0.f ? e1 : NEG * e1);
        den += w0 + w1;
        __half2 w20 = __float2half2_rn(w0), w21 = __float2half2_rn(w1);
        acc0 = __hfma2(w20, *(__half2*)&u0.x, acc0);
        acc1 = __hfma2(w20, *(__half2*)&u0.y, acc1);
        acc0 = __hfma2(w21, *(__half2*)&u1.x, acc0);
        acc1 = __hfma2(w21, *(__half2*)&u1.y, acc1);
    }
    if (i < deg) {
        int s = col[start + i];
        uint2 u = *(const uint2*)(hb + ((unsigned)s << 5) + co);
        float e = alsrc[s * 4 + head] + ad;
        float w = __expf(e > 0.f ? e : NEG * e);
        den += w;
        __half2 w2 = __float2half2_rn(w);
        acc0 = __hfma2(w2, *(__half2*)&u.x, acc0);
        acc1 = __hfma2(w2, *(__half2*)&u.y, acc1);
    }
    float2 f0 = __half22float2(acc0), f1 = __half22float2(acc1);
    float a0 = f0.x, a1 = f0.y, a2 = f1.x, a3 = f1.y;
    #pragma unroll
    for (int off = 16; off <= 32; off <<= 1) {
        a0 += __shfl_xor(a0, off); a1 += __shfl_xor(a1, off);
        a2 += __shfl_xor(a2, off); a3 += __shfl_xor(a3, off);
        den += __shfl_xor(den, off);
    }
    if (lane < 16) {
        float inv = 1.f / den;
        float4 b = *(const float4*)(bias + 4 * c);
        __half2 o0 = __floats2half2_rn(a0 * inv + b.x, a1 * inv + b.y);
        __half2 o1 = __floats2half2_rn(a2 * inv + b.z, a3 * inv + b.w);
        uint2 o; o.x = *(unsigned*)&o0; o.y = *(unsigned*)&o1;
        *(uint2*)(out + (size_t)d * 64 + 4 * c) = o;
    }
}

// ---------------- Layer 2 GEMM: h2 = h1o(fp16) @ W2 (fp16 out), register-tiled ----------------

__global__ __launch_bounds__(256) void gemm2_k(const __half* __restrict__ xh, const float* __restrict__ W,
                                               const float* __restrict__ a_src, const float* __restrict__ a_dst,
                                               __half* __restrict__ h, float* __restrict__ alsrc,
                                               float* __restrict__ aldst, int N) {
    __shared__ float Bs[64 * 128];
    __shared__ float xs[64][68];
    int t = threadIdx.x;
    for (int i = t; i < 64 * 128 / 4; i += 256)
        ((float4*)Bs)[i] = ((const float4*)W)[i];
    int ct = t & 15, rt = t >> 4;
    int hA = ct >> 3, cq = ct & 7;
    float asA[4], adA[4], asB[4], adB[4];
    #pragma unroll
    for (int j = 0; j < 4; j++) {
        asA[j] = a_src[hA * 32 + 4 * cq + j];
        adA[j] = a_dst[hA * 32 + 4 * cq + j];
        asB[j] = a_src[(2 + hA) * 32 + 4 * cq + j];
        adB[j] = a_dst[(2 + hA) * 32 + 4 * cq + j];
    }
    int ntiles = (N + 63) >> 6;
    for (int tile = blockIdx.x; tile < ntiles; tile += gridDim.x) {
        int r0 = tile << 6;
        float accA[4][4], accB[4][4];
        #pragma unroll
        for (int i = 0; i < 4; i++)
            #pragma unroll
            for (int j = 0; j < 4; j++) { accA[i][j] = 0.f; accB[i][j] = 0.f; }
        __syncthreads();
        int srow = t >> 3, su = t & 7;
        #pragma unroll
        for (int p = 0; p < 2; p++) {
            int r = r0 + srow + 32 * p;
            float2 g0 = make_float2(0.f, 0.f), g1 = g0, g2 = g0, g3 = g0;
            if (r < N) {
                uint4 u = *(const uint4*)(xh + (size_t)r * 64 + 8 * su);
                const __half2* hp = (const __half2*)&u;
                g0 = __half22float2(hp[0]); g1 = __half22float2(hp[1]);
                g2 = __half22float2(hp[2]); g3 = __half22float2(hp[3]);
            }
            *(float4*)&xs[srow + 32 * p][8 * su] = make_float4(g0.x, g0.y, g1.x, g1.y);
            *(float4*)&xs[srow + 32 * p][8 * su + 4] = make_float4(g2.x, g2.y, g3.x, g3.y);
        }
        __syncthreads();
        #pragma unroll 4
        for (int k = 0; k < 64; k++) {
            float4 bA = *(float4*)&Bs[k * 128 + 4 * ct];
            float4 bB = *(float4*)&Bs[k * 128 + 64 + 4 * ct];
            #pragma unroll
            for (int i = 0; i < 4; i++) {
                float xv = xs[4 * rt + i][k];
                accA[i][0] = fmaf(xv, bA.x, accA[i][0]);
                accA[i][1] = fmaf(xv, bA.y, accA[i][1]);
                accA[i][2] = fmaf(xv, bA.z, accA[i][2]);
                accA[i][3] = fmaf(xv, bA.w, accA[i][3]);
                accB[i][0] = fmaf(xv, bB.x, accB[i][0]);
                accB[i][1] = fmaf(xv, bB.y, accB[i][1]);
                accB[i][2] = fmaf(xv, bB.z, accB[i][2]);
                accB[i][3] = fmaf(xv, bB.w, accB[i][3]);
            }
        }
        #pragma unroll
        for (int i = 0; i < 4; i++) {
            int r = r0 + 4 * rt + i;
            float psA = 0.f, pdA = 0.f, psB = 0.f, pdB = 0.f;
            #pragma unroll
            for (int j = 0; j < 4; j++) {
                psA = fmaf(accA[i][j], asA[j], psA);
                pdA = fmaf(accA[i][j], adA[j], pdA);
                psB = fmaf(accB[i][j], asB[j], psB);
                pdB = fmaf(accB[i][j], adB[j], pdB);
            }
            #pragma unroll
            for (int off = 1; off <= 4; off <<= 1) {
                psA += __shfl_xor(psA, off); pdA += __shfl_xor(pdA, off);
                psB += __shfl_xor(psB, off); pdB += __shfl_xor(pdB, off);
            }
            if (r < N) {
                __half2 hA0 = __floats2half2_rn(accA[i][0], accA[i][1]);
                __half2 hA1 = __floats2half2_rn(accA[i][2], accA[i][3]);
                __half2 hB0 = __floats2half2_rn(accB[i][0], accB[i][1]);
                __half2 hB1 = __floats2half2_rn(accB[i][2], accB[i][3]);
                *(__half2*)(h + (size_t)r * 128 + 4 * ct) = hA0;
                *(__half2*)(h + (size_t)r * 128 + 4 * ct + 2) = hA1;
                *(__half2*)(h + (size_t)r * 128 + 64 + 4 * ct) = hB0;
                *(__half2*)(h + (size_t)r * 128 + 64 + 4 * ct + 2) = hB1;
                if (cq == 0) {
                    alsrc[r * 4 + hA] = psA;     alsrc[r * 4 + 2 + hA] = psB;
                    aldst[r * 4 + hA] = pdA;     aldst[r * 4 + 2 + hA] = pdB;
                }
            }
        }
    }
}

// ---------------- Layer 2 node aggregation (2-edge pipelined) + epilogue ----------------

__global__ __launch_bounds__(256) void node2_k(const __half* __restrict__ h, const float* __restrict__ alsrc,
                                               const float* __restrict__ aldst, const int* __restrict__ rp,
                                               const int* __restrict__ cnt, const int* __restrict__ col,
                                               const float* __restrict__ bias, float* __restrict__ out, int N) {
    int wid = (blockIdx.x * 256 + threadIdx.x) >> 6;
    int lane = threadIdx.x & 63;
    if (wid >= N) return;
    int d = wid;
    int g = lane >> 4;
    int c = lane & 15;
    int head = c >> 2;
    float ad = aldst[d * 4 + head];
    float den = 0.f;
    __half2 acc[4];
    #pragma unroll
    for (int j = 0; j < 4; j++) acc[j] = __float2half2_rn(0.f);
    const __half2* hb = (const __half2*)h;
    unsigned co = 4u * c;
    if (g == 0) {  // self loop
        float e0 = alsrc[d * 4 + head] + ad;
        float w = __expf(e0 > 0.f ? e0 : NEG * e0);
        den = w;
        __half2 w2 = __float2half2_rn(w);
        uint4 u = *(const uint4*)(hb + ((unsigned)d << 6) + co);
        const __half2* hp = (const __half2*)&u;
        #pragma unroll
        for (int j = 0; j < 4; j++) acc[j] = __hfma2(w2, hp[j], acc[j]);
    }
    int start = rp[d], deg = cnt[d];
    int i = g;
    for (; i + 4 < deg; i += 8) {
        int s0 = col[start + i];
        int s1 = col[start + i + 4];
        uint4 u0 = *(const uint4*)(hb + ((unsigned)s0 << 6) + co);
        uint4 u1 = *(const uint4*)(hb + ((unsigned)s1 << 6) + co);
        float e0 = alsrc[s0 * 4 + head] + ad;
        float e1 = alsrc[s1 * 4 + head] + ad;
        float w0 = __expf(e0 > 0.f ? e0 : NEG * e0);
        float w1 = __expf(e1 > 0.f ? e1 : NEG * e1);
        den += w0 + w1;
        __half2 w20 = __float2half2_rn(w0), w21 = __float2half2_rn(w1);
        const __half2* hp0 = (const __half2*)&u0;
        const __half2* hp1 = (const __half2*)&u1;
        #pragma unroll
        for (int j = 0; j < 4; j++) acc[j] = __hfma2(w20, hp0[j], acc[j]);
        #pragma unroll
        for (int j = 0; j < 4; j++) acc[j] = __hfma2(w21, hp1[j], acc[j]);
    }
    if (i < deg) {
        int s = col[start + i];
        uint4 u = *(const uint4*)(hb + ((unsigned)s << 6) + co);
        float e = alsrc[s * 4 + head] + ad;
        float w = __expf(e > 0.f ? e : NEG * e);
        den += w;
        __half2 w2 = __float2half2_rn(w);
        const __half2* hp = (const __half2*)&u;
        #pragma unroll
        for (int j = 0; j < 4; j++) acc[j] = __hfma2(w2, hp[j], acc[j]);
    }
    float a[8];
    #pragma unroll
    for (int j = 0; j < 4; j++) {
        float2 f = __half22float2(acc[j]);
        a[2 * j] = f.x; a[2 * j + 1] = f.y;
    }
    #pragma unroll
    for (int off = 16; off <= 32; off <<= 1) {
        #pragma unroll
        for (int j = 0; j < 8; j++) a[j] += __shfl_xor(a[j], off);
        den += __shfl_xor(den, off);
    }
    float inv = 1.f / den;
    float v[8];
    #pragma unroll
    for (int j = 0; j < 8; j++) v[j] = a[j] * inv;
    #pragma unroll
    for (int off = 4; off <= 8; off <<= 1) {
        #pragma unroll
        for (int j = 0; j < 8; j++) v[j] += __shfl_xor(v[j], off);
    }
    int jc = c & 3;
    float ev[8];
    #pragma unroll
    for (int j = 0; j < 8; j++) {
        float val = 0.25f * v[j] + bias[8 * jc + j];
        ev[j] = val > 0.f ? val : expm1f(val);
    }
    float mx = ev[0];
    #pragma unroll
    for (int j = 1; j < 8; j++) mx = fmaxf(mx, ev[j]);
    #pragma unroll
    for (int off = 1; off <= 2; off <<= 1) mx = fmaxf(mx, __shfl_xor(mx, off));
    float sum = 0.f;
    #pragma unroll
    for (int j = 0; j < 8; j++) sum += __expf(ev[j] - mx);
    #pragma unroll
    for (int off = 1; off <= 2; off <<= 1) sum += __shfl_xor(sum, off);
    float ls = mx + __logf(sum);
    if (lane < 4) {
        float4 o0, o1;
        o0.x = ev[0] - ls; o0.y = ev[1] - ls; o0.z = ev[2] - ls; o0.w = ev[3] - ls;
        o1.x = ev[4] - ls; o1.y = ev[5] - ls; o1.z = ev[6] - ls; o1.w = ev[7] - ls;
        *(float4*)(out + (size_t)d * 32 + 8 * jc) = o0;
        *(float4*)(out + (size_t)d * 32 + 8 * jc + 4) = o1;
    }
}

// ---------------- launch ----------------

extern "C" void kernel_launch(void* const* d_in, const int* in_sizes, int n_in,
                              void* d_out, int out_size, void* d_ws, size_t ws_size,
                              hipStream_t stream) {
    const float* x   = (const float*)d_in[0];
    const int*   ei  = (const int*)d_in[1];
    const float* W1  = (const float*)d_in[2];
    const float* as1 = (const float*)d_in[3];
    const float* ad1 = (const float*)d_in[4];
    const float* b1  = (const float*)d_in[5];
    const float* W2  = (const float*)d_in[6];
    const float* as2 = (const float*)d_in[7];
    const float* ad2 = (const float*)d_in[8];
    const float* b2  = (const float*)d_in[9];
    float* out = (float*)d_out;
    int N = in_sizes[0] / 128;
    int E = in_sizes[1] / 2;

    char* base = (char*)d_ws;
    size_t off = 0;
    auto alloc = [&](size_t bytes) -> char* {
        char* p = base + off;
        off = (off + bytes + 255) & ~(size_t)255;
        return p;
    };
    __half* h1h   = (__half*)alloc((size_t)N * 64 * 2);
    __half* h2h   = (__half*)alloc((size_t)N * 128 * 2);
    __half* h1o   = (__half*)alloc((size_t)N * 64 * 2);
    float* alsrc1 = (float*)alloc((size_t)N * 4 * 4);
    float* aldst1 = (float*)alloc((size_t)N * 4 * 4);
    float* alsrc2 = (float*)alloc((size_t)N * 4 * 4);
    float* aldst2 = (float*)alloc((size_t)N * 4 * 4);
    int* cnt  = (int*)alloc((size_t)N * 4);
    int* rp   = (int*)alloc((size_t)N * 4);
    int* curA = (int*)alloc(256 * 4);
    int* bs   = (int*)alloc(1024 * 4);
    int* col  = (int*)alloc((size_t)E * 4);
    uint2* pairs = (uint2*)alloc((size_t)E * 8);

    int nbk = (N + 511) >> 9;       // 512-node buckets
    int ntilesA = (E + TILE - 1) / TILE;
    int nb = (N + 255) / 256;

    hipMemsetAsync(cnt, 0, (size_t)N * 4, stream);
    hist_k<<<(E + 255) / 256, 256, 0, stream>>>(ei, cnt, E);
    scan1_k<<<nb, 256, 0, stream>>>(cnt, rp, bs, N);
    scan2_k<<<1, 1024, 0, stream>>>(bs, nb);
    scan3_k<<<nb, 256, 0, stream>>>(rp, bs, N);
    initA_k<<<1, 256, 0, stream>>>(rp, curA, nbk);
    partA_k<<<ntilesA, 256, 0, stream>>>(ei, curA, pairs, E, nbk);
    partB_k<<<nbk, 256, 0, stream>>>(pairs, rp, col, E, N);

    gemm1_k<<<768, 256, 0, stream>>>(x, W1, as1, ad1, h1h, alsrc1, aldst1, N);
    node1_k<<<(N + 3) / 4, 256, 0, stream>>>(h1h, alsrc1, aldst1, rp, cnt, col, b1, h1o, N);
    gemm2_k<<<768, 256, 0, stream>>>(h1o, W2, as2, ad2, h2h, alsrc2, aldst2, N);
    node2_k<<<(N + 3) / 4, 256, 0, stream>>>(h2h, alsrc2, aldst2, rp, cnt, col, b2, out, N);
}